// Round 6
// baseline (1874.635 us; speedup 1.0000x reference)
//
#include <hip/hip_runtime.h>
#include <hip/hip_bf16.h>

typedef __bf16 bf16_t;
typedef __bf16 bf16x4 __attribute__((ext_vector_type(4)));
typedef __bf16 bf16x8 __attribute__((ext_vector_type(8)));
typedef float f32x4 __attribute__((ext_vector_type(4)));

constexpr int T_STEPS = 50;
constexpr int B_SZ = 1024;
constexpr int NP_SZ = 512;
constexpr int NH_SZ = 512;
constexpr int NG_SZ = 4096;

// async 16B/lane global->LDS. LDS dest is wave-uniform base; HW deposits lane i at base + i*16.
__device__ __forceinline__ void async16(const bf16_t* g, bf16_t* l) {
    __builtin_amdgcn_global_load_lds((const __attribute__((address_space(1))) void*)g,
                                     (__attribute__((address_space(3))) void*)l, 16, 0, 0);
}

// Fused counted-vmcnt wait + workgroup barrier in ONE asm block with "memory" clobber.
// The builtin s_barrier is NOT a compiler memory fence: ds_reads and global_load_lds
// issues can be scheduled across it (r5 race: tile t+D's LDS write hoisted above the
// barrier landed while a slow wave still read tile t-1 from the same buffer). The
// memory clobber pins all memory ops on their side; sched_barrier(0) pins the rest.
template <int N> __device__ __forceinline__ void wbar() {
    if constexpr (N == 0)       asm volatile("s_waitcnt vmcnt(0)\n\ts_barrier" ::: "memory");
    else if constexpr (N == 6)  asm volatile("s_waitcnt vmcnt(6)\n\ts_barrier" ::: "memory");
    else if constexpr (N == 12) asm volatile("s_waitcnt vmcnt(12)\n\ts_barrier" ::: "memory");
    else if constexpr (N == 18) asm volatile("s_waitcnt vmcnt(18)\n\ts_barrier" ::: "memory");
    else if constexpr (N == 24) asm volatile("s_waitcnt vmcnt(24)\n\ts_barrier" ::: "memory");
    else static_assert(N < 0, "add vmcnt literal");
    __builtin_amdgcn_sched_barrier(0);
}

// ---------------- fp32 -> bf16 convert ----------------
__global__ __launch_bounds__(256) void cvt_f32_bf16(const float* __restrict__ src,
                                                    bf16_t* __restrict__ dst, int n4) {
    int i = blockIdx.x * blockDim.x + threadIdx.x;
    if (i >= n4) return;
    float4 v = ((const float4*)src)[i];
    bf16x4 o;
    o[0] = (bf16_t)v.x; o[1] = (bf16_t)v.y; o[2] = (bf16_t)v.z; o[3] = (bf16_t)v.w;
    ((bf16x4*)dst)[i] = o;
}

// ---------------- counted-vmcnt depth-D GEMM: C = ep(A[M,K] @ B[N,K]^T) ----------------
// LDS fragment order: chunk = 16 rows x 32 cols = 64 lanes x 16B; lane l holds rows
// (s*16+(l&15)), cols (l>>4)*8.. == its MFMA fragment. NBUF = DEPTH+1 buffers, DEPTH
// tiles in flight; per-iter: wbar<(DEPTH-1)*PW> (tile t landed, t+1..t+D-1 flying,
// all waves agree) -> issue tile t+DEPTH -> ds_read+MFMA tile t. vmcnt never drains
// to 0 in the main loop (T4). Tail: one full drain, last DEPTH tiles barrier-free.
// Launcher guarantees nk = K/32 > DEPTH.
// SWZ: 0 = none | 2 = A-panel XCD affinity (hw XCD owns logical rows by%8==xcd; needs
//      gridDim.y % 8 == 0) so the gridDim.x blocks sharing an A-panel hit one L2.
// EP: 0 = +bias f32 out | 1 = +bias bf16 out | 2 = relu bf16 out
template <int BM, int BN, int DEPTH, int EP, int SWZ>
__global__ __launch_bounds__(256) void gemm16(const bf16_t* __restrict__ A,
                                              const bf16_t* __restrict__ Bm,
                                              const float* __restrict__ bias,
                                              void* __restrict__ Cout, int M, int N, int K) {
    constexpr int ASUB = BM / 16, BSUB = BN / 16, NSUB = ASUB + BSUB;
    static_assert(NSUB % 4 == 0, "subtile split over 4 waves");
    constexpr int PW = NSUB / 4;  // staged chunks per wave per tile
    constexpr int MT = BM / 32, NT = BN / 32;
    constexpr int BUF = NSUB * 512;
    constexpr int NBUF = DEPTH + 1;
    __shared__ bf16_t lds[NBUF * BUF];

    const int tid = threadIdx.x, lane = tid & 63, wave = tid >> 6;
    const int wm = wave >> 1, wn = wave & 1;
    const int l15 = lane & 15, quad = lane >> 4;

    int bx = blockIdx.x, by = blockIdx.y;
    if constexpr (SWZ == 2) {
        // hw id -> (xcd, slot); xcd owns logical rows by ≡ xcd (mod 8), bx fastest.
        const int hwid = by * gridDim.x + bx;
        const int xcd = hwid & 7, j = hwid >> 3;
        bx = j % gridDim.x;
        by = xcd + 8 * (j / gridDim.x);
    }
    const int bm0 = by * BM, bn0 = bx * BN;

    // per-lane staging source pointers (advance by 32 elems per K-iter)
    const bf16_t* gsrc[PW];
    bf16_t* ldst[PW];
#pragma unroll
    for (int q = 0; q < PW; q++) {
        int s = wave * PW + q;
        if (s < ASUB)
            gsrc[q] = A + (size_t)(bm0 + s * 16 + l15) * K + quad * 8;
        else
            gsrc[q] = Bm + (size_t)(bn0 + (s - ASUB) * 16 + l15) * K + quad * 8;
        ldst[q] = &lds[s * 512];
    }

    f32x4 acc[MT][NT];
#pragma unroll
    for (int i = 0; i < MT; i++)
#pragma unroll
        for (int j = 0; j < NT; j++) acc[i][j] = f32x4{0.f, 0.f, 0.f, 0.f};

    auto compute = [&](int base) {
        bf16x8 af[MT], bfg[NT];
#pragma unroll
        for (int i = 0; i < MT; i++)
            af[i] = *(const bf16x8*)&lds[base + (wm * MT + i) * 512 + lane * 8];
#pragma unroll
        for (int j = 0; j < NT; j++)
            bfg[j] = *(const bf16x8*)&lds[base + (ASUB + wn * NT + j) * 512 + lane * 8];
#pragma unroll
        for (int i = 0; i < MT; i++)
#pragma unroll
            for (int j = 0; j < NT; j++)
                acc[i][j] = __builtin_amdgcn_mfma_f32_16x16x32_bf16(af[i], bfg[j], acc[i][j], 0, 0, 0);
    };

    const int nk = K / 32;  // launcher guarantees nk > DEPTH
    // prologue: tiles 0..DEPTH-1 into buffers 0..DEPTH-1
#pragma unroll
    for (int d = 0; d < DEPTH; d++)
#pragma unroll
        for (int q = 0; q < PW; q++) async16(gsrc[q] + d * 32, ldst[q] + d * BUF);

    int cb = 0;  // buffer holding tile t
    for (int t = 0; t < nk - DEPTH; t++) {
        wbar<(DEPTH - 1) * PW>();      // tile t landed everywhere; t+1.. still flying
        int ib = cb + DEPTH; if (ib >= NBUF) ib -= NBUF;
#pragma unroll
        for (int q = 0; q < PW; q++) async16(gsrc[q] + (t + DEPTH) * 32, ldst[q] + ib * BUF);
        compute(cb * BUF);
        cb++; if (cb == NBUF) cb = 0;
    }
    // tail: all remaining tiles already issued; one drain, then barrier-free compute
    wbar<0>();
    for (int t2 = 0; t2 < DEPTH; t2++) {
        compute(cb * BUF);
        cb++; if (cb == NBUF) cb = 0;
    }

// epilogue: C/D layout col=lane&15, row=quad*4+reg
#pragma unroll
    for (int j = 0; j < NT; j++) {
        const int col = bn0 + wn * (BN / 2) + j * 16 + l15;
        float bb = (EP == 2) ? 0.f : bias[col];
#pragma unroll
        for (int i = 0; i < MT; i++) {
#pragma unroll
            for (int r = 0; r < 4; r++) {
                const int row = bm0 + wm * (BM / 2) + i * 16 + quad * 4 + r;
                float x = acc[i][j][r];
                if constexpr (EP == 0) {
                    ((float*)Cout)[(size_t)row * N + col] = x + bb;
                } else if constexpr (EP == 1) {
                    ((bf16_t*)Cout)[(size_t)row * N + col] = (bf16_t)(x + bb);
                } else {
                    ((bf16_t*)Cout)[(size_t)row * N + col] = (bf16_t)fmaxf(x, 0.f);
                }
            }
        }
    }
}

// ---------------- fused gates GEMM + LSTM cell ----------------
// Block computes a 64(row b) x 32(col n) tile of hx/cx; accumulates all 4 gate slices
// of w_hh. Grid (16,16) = 256 blocks. Counted-vmcnt DEPTH=7 pipeline (8 bufs, 96 KB).
__global__ __launch_bounds__(256) void gates_cell(
    const bf16_t* __restrict__ hx_in, const bf16_t* __restrict__ whh,
    const float* __restrict__ vt, const float* __restrict__ wih,
    const float* __restrict__ bih, const float* __restrict__ bhh,
    float* __restrict__ cx, bf16_t* __restrict__ hx_out) {
    // chunks: 0..3 = A (64 rows of hx), 4..11 = B (4 gates x 2 halves of 32 n-cols)
    constexpr int NCH = 12, BUF = NCH * 512, PW = 3;
    constexpr int DEPTH = 7, NBUF = DEPTH + 1;
    __shared__ bf16_t lds[NBUF * BUF];
    const int tid = threadIdx.x, lane = tid & 63, wave = tid >> 6;
    const int wm = wave >> 1, wn = wave & 1;
    const int l15 = lane & 15, quad = lane >> 4;
    const int bm0 = blockIdx.y * 64, bn0 = blockIdx.x * 32;

    const bf16_t* gsrc[PW];
    bf16_t* ldst[PW];
#pragma unroll
    for (int q = 0; q < PW; q++) {
        int s = wave * PW + q;
        if (s < 4) {
            gsrc[q] = hx_in + (size_t)(bm0 + s * 16 + l15) * NH_SZ + quad * 8;
        } else {
            int sb = s - 4, gi = sb >> 1, h = sb & 1;
            gsrc[q] = whh + (size_t)(gi * NH_SZ + bn0 + h * 16 + l15) * NH_SZ + quad * 8;
        }
        ldst[q] = &lds[s * 512];
    }

    f32x4 acc[4][2];
#pragma unroll
    for (int g = 0; g < 4; g++)
#pragma unroll
        for (int i = 0; i < 2; i++) acc[g][i] = f32x4{0.f, 0.f, 0.f, 0.f};

    auto compute = [&](int base) {
        bf16x8 af[2], bg[4];
#pragma unroll
        for (int i = 0; i < 2; i++)
            af[i] = *(const bf16x8*)&lds[base + (wm * 2 + i) * 512 + lane * 8];
#pragma unroll
        for (int g = 0; g < 4; g++)
            bg[g] = *(const bf16x8*)&lds[base + (4 + g * 2 + wn) * 512 + lane * 8];
#pragma unroll
        for (int g = 0; g < 4; g++)
#pragma unroll
            for (int i = 0; i < 2; i++)
                acc[g][i] = __builtin_amdgcn_mfma_f32_16x16x32_bf16(af[i], bg[g], acc[g][i], 0, 0, 0);
    };

    constexpr int NK = NH_SZ / 32;  // 16 > DEPTH
#pragma unroll
    for (int d = 0; d < DEPTH; d++)
#pragma unroll
        for (int q = 0; q < PW; q++) async16(gsrc[q] + d * 32, ldst[q] + d * BUF);

    int cb = 0;
    for (int t = 0; t < NK - DEPTH; t++) {
        wbar<(DEPTH - 1) * PW>();
        int ib = cb + DEPTH; if (ib >= NBUF) ib -= NBUF;
#pragma unroll
        for (int q = 0; q < PW; q++) async16(gsrc[q] + (t + DEPTH) * 32, ldst[q] + ib * BUF);
        compute(cb * BUF);
        cb++; if (cb == NBUF) cb = 0;
    }
    wbar<0>();
    for (int t2 = 0; t2 < DEPTH; t2++) {
        compute(cb * BUF);
        cb++; if (cb == NBUF) cb = 0;
    }

    const int col = bn0 + wn * 16 + l15;
    float bi[4], w0[4], w1[4];
#pragma unroll
    for (int g = 0; g < 4; g++) {
        int gc = g * NH_SZ + col;
        bi[g] = bih[gc] + bhh[gc];
        w0[g] = wih[gc * 2];
        w1[g] = wih[gc * 2 + 1];
    }
#pragma unroll
    for (int i = 0; i < 2; i++) {
#pragma unroll
        for (int r = 0; r < 4; r++) {
            const int row = bm0 + wm * 32 + i * 16 + quad * 4 + r;
            float v0 = vt[row * 2], v1 = vt[row * 2 + 1];
            float xi = acc[0][i][r] + bi[0] + v0 * w0[0] + v1 * w1[0];
            float xf = acc[1][i][r] + bi[1] + v0 * w0[1] + v1 * w1[1];
            float xg = acc[2][i][r] + bi[2] + v0 * w0[2] + v1 * w1[2];
            float xo = acc[3][i][r] + bi[3] + v0 * w0[3] + v1 * w1[3];
            float ig = 1.f / (1.f + __expf(-xi));
            float fg = 1.f / (1.f + __expf(-xf));
            float gg = tanhf(xg);
            float og = 1.f / (1.f + __expf(-xo));
            int idx = (row << 9) + col;
            float c = fg * cx[idx] + ig * gg;
            cx[idx] = c;
            hx_out[idx] = (bf16_t)(og * tanhf(c));
        }
    }
}

// ---------------- host launcher ----------------
extern "C" void kernel_launch(void* const* d_in, const int* in_sizes, int n_in,
                              void* d_out, int out_size, void* d_ws, size_t ws_size,
                              hipStream_t stream) {
    const float* v    = (const float*)d_in[0];
    const float* p0   = (const float*)d_in[1];
    const float* e1w  = (const float*)d_in[2];
    const float* e1b  = (const float*)d_in[3];
    const float* e2w  = (const float*)d_in[4];
    const float* e2b  = (const float*)d_in[5];
    const float* wih  = (const float*)d_in[6];
    const float* whh  = (const float*)d_in[7];
    const float* bih  = (const float*)d_in[8];
    const float* bhh  = (const float*)d_in[9];
    const float* gw   = (const float*)d_in[10];
    const float* decw = (const float*)d_in[11];
    const float* decb = (const float*)d_in[12];
    float* out = (float*)d_out;

    size_t off = 0;
    auto take = [&](size_t bytes) {
        size_t o = off;
        off += (bytes + 255) & ~(size_t)255;
        return (void*)((char*)d_ws + o);
    };
    bf16_t* p0b   = (bf16_t*)take((size_t)B_SZ * NP_SZ * 2);
    bf16_t* e1wb  = (bf16_t*)take((size_t)NH_SZ * NP_SZ * 2);
    bf16_t* e2wb  = (bf16_t*)take((size_t)NH_SZ * NP_SZ * 2);
    bf16_t* whhb  = (bf16_t*)take((size_t)4 * NH_SZ * NH_SZ * 2);
    bf16_t* gwb   = (bf16_t*)take((size_t)NG_SZ * NH_SZ * 2);
    bf16_t* decwb = (bf16_t*)take((size_t)NP_SZ * NG_SZ * 2);
    bf16_t* hxA   = (bf16_t*)take((size_t)B_SZ * NH_SZ * 2);
    bf16_t* hxB   = (bf16_t*)take((size_t)B_SZ * NH_SZ * 2);
    float*  cxf   = (float*)take((size_t)B_SZ * NH_SZ * 4);

    // decoder chunk size: largest divisor of T that fits remaining workspace
    const size_t per_step = (size_t)B_SZ * NG_SZ * 2;  // 8 MB bf16
    int C = 1;
    for (int c : {25, 10, 5, 2, 1}) {
        if (off + (size_t)c * per_step <= ws_size) { C = c; break; }
    }
    bf16_t* gbuf = (bf16_t*)take((size_t)C * per_step);

    auto cvt = [&](const float* s, bf16_t* d, int n) {
        int n4 = n >> 2;
        cvt_f32_bf16<<<dim3((n4 + 255) / 256), dim3(256), 0, stream>>>(s, d, n4);
    };
    cvt(p0, p0b, B_SZ * NP_SZ);
    cvt(e1w, e1wb, NH_SZ * NP_SZ);
    cvt(e2w, e2wb, NH_SZ * NP_SZ);
    cvt(whh, whhb, 4 * NH_SZ * NH_SZ);
    cvt(gw, gwb, NG_SZ * NH_SZ);
    cvt(decw, decwb, NP_SZ * NG_SZ);

    // encoders: hx0 (bf16), cx0 (f32). 64x64 tiles -> 128 blocks each, depth-4.
    gemm16<64, 64, 4, 1, 0><<<dim3(NH_SZ / 64, B_SZ / 64), 256, 0, stream>>>(
        p0b, e1wb, e1b, hxA, B_SZ, NH_SZ, NP_SZ);
    gemm16<64, 64, 4, 0, 0><<<dim3(NH_SZ / 64, B_SZ / 64), 256, 0, stream>>>(
        p0b, e2wb, e2b, cxf, B_SZ, NH_SZ, NP_SZ);

    bf16_t* hin = hxA;
    bf16_t* hout = hxB;
    for (int t = 0; t < T_STEPS; t++) {
        const float* vt = v + (size_t)t * B_SZ * 2;
        // fused gates + cell: grid (NH/32, B/64) = (16,16) = 256 blocks, depth-7
        gates_cell<<<dim3(NH_SZ / 32, B_SZ / 64), 256, 0, stream>>>(
            hin, whhb, vt, wih, bih, bhh, cxf, hout);
        // g = relu(hx @ g_w^T): 128x128 tiles -> (32,8) = 256 blocks, depth-7,
        // A-affinity swizzle (gy=8 % 8 == 0)
        gemm16<128, 128, 7, 2, 2><<<dim3(NG_SZ / 128, B_SZ / 128), 256, 0, stream>>>(
            hout, gwb, nullptr, gbuf + (size_t)(t % C) * B_SZ * NG_SZ, B_SZ, NG_SZ, NH_SZ);
        // chunked batched decoder: 128x128 tiles (800 blocks), depth-4 (80 KB -> 2/CU),
        // A-affinity swizzle (gy in {200,80,40,16,8}, all % 8 == 0)
        if ((t + 1) % C == 0) {
            int t0 = t + 1 - C;
            gemm16<128, 128, 4, 0, 2><<<dim3(NP_SZ / 128, (C * B_SZ) / 128), 256, 0, stream>>>(
                gbuf, decwb, decb, out + (size_t)t0 * B_SZ * NP_SZ, C * B_SZ, NP_SZ, NG_SZ);
        }
        // swap hx buffers
        bf16_t* tmp = hin; hin = hout; hout = tmp;
    }
}

// Round 7
// 1727.682 us; speedup vs baseline: 1.0851x; 1.0851x over previous
//
#include <hip/hip_runtime.h>
#include <hip/hip_bf16.h>

typedef __bf16 bf16_t;
typedef __bf16 bf16x4 __attribute__((ext_vector_type(4)));
typedef __bf16 bf16x8 __attribute__((ext_vector_type(8)));
typedef float f32x4 __attribute__((ext_vector_type(4)));

constexpr int T_STEPS = 50;
constexpr int B_SZ = 1024;
constexpr int NP_SZ = 512;
constexpr int NH_SZ = 512;
constexpr int NG_SZ = 4096;

// async 16B/lane global->LDS. LDS dest is wave-uniform base; HW deposits lane i at base + i*16.
__device__ __forceinline__ void async16(const bf16_t* g, bf16_t* l) {
    __builtin_amdgcn_global_load_lds((const __attribute__((address_space(1))) void*)g,
                                     (__attribute__((address_space(3))) void*)l, 16, 0, 0);
}

// Fused counted-vmcnt wait + workgroup barrier in ONE asm block with "memory" clobber.
// The builtin s_barrier is NOT a compiler memory fence: ds_reads and global_load_lds
// issues can be scheduled across it (r5 race). The memory clobber pins all memory ops
// on their side; sched_barrier(0) pins the rest.
template <int N> __device__ __forceinline__ void wbar() {
    if constexpr (N == 0)       asm volatile("s_waitcnt vmcnt(0)\n\ts_barrier" ::: "memory");
    else if constexpr (N == 2)  asm volatile("s_waitcnt vmcnt(2)\n\ts_barrier" ::: "memory");
    else if constexpr (N == 3)  asm volatile("s_waitcnt vmcnt(3)\n\ts_barrier" ::: "memory");
    else if constexpr (N == 4)  asm volatile("s_waitcnt vmcnt(4)\n\ts_barrier" ::: "memory");
    else if constexpr (N == 6)  asm volatile("s_waitcnt vmcnt(6)\n\ts_barrier" ::: "memory");
    else if constexpr (N == 8)  asm volatile("s_waitcnt vmcnt(8)\n\ts_barrier" ::: "memory");
    else if constexpr (N == 12) asm volatile("s_waitcnt vmcnt(12)\n\ts_barrier" ::: "memory");
    else static_assert(N < 0, "add vmcnt literal");
    __builtin_amdgcn_sched_barrier(0);
}

// ---------------- fp32 -> bf16 convert ----------------
__global__ __launch_bounds__(256) void cvt_f32_bf16(const float* __restrict__ src,
                                                    bf16_t* __restrict__ dst, int n4) {
    int i = blockIdx.x * blockDim.x + threadIdx.x;
    if (i >= n4) return;
    float4 v = ((const float4*)src)[i];
    bf16x4 o;
    o[0] = (bf16_t)v.x; o[1] = (bf16_t)v.y; o[2] = (bf16_t)v.z; o[3] = (bf16_t)v.w;
    ((bf16x4*)dst)[i] = o;
}

// ---------------- counted-vmcnt depth-D GEMM: C = ep(A[M,K] @ B[N,K]^T) ----------------
// WM x WN wave grid (WM*WN waves, 64*WM*WN threads). LDS fragment order: chunk =
// 16 rows x 32 cols = 64 lanes x 16B; lane l holds rows (s*16+(l&15)), cols (l>>4)*8..
// == its MFMA fragment. NBUF = DEPTH+1 buffers, DEPTH tiles in flight; per-iter:
// wbar<(DEPTH-1)*PW> (tile t landed everywhere, t+1..t+D-1 flying) -> issue tile
// t+DEPTH -> ds_read+MFMA tile t. vmcnt never drains to 0 in the main loop (T4).
// Tail: one full drain, last DEPTH tiles barrier-free. Launcher guarantees nk > DEPTH.
// SWZ: 0 = none | 2 = A-panel XCD affinity (hw XCD owns logical rows by%8==xcd; needs
//      gridDim.y % 8 == 0) so the gridDim.x blocks sharing an A-panel hit one L2.
// EP: 0 = +bias f32 out | 1 = +bias bf16 out | 2 = relu bf16 out
template <int BM, int BN, int WM, int WN, int DEPTH, int EP, int SWZ>
__global__ __launch_bounds__(WM * WN * 64) void gemm16(const bf16_t* __restrict__ A,
                                                       const bf16_t* __restrict__ Bm,
                                                       const float* __restrict__ bias,
                                                       void* __restrict__ Cout, int M, int N, int K) {
    constexpr int ASUB = BM / 16, BSUB = BN / 16, NSUB = ASUB + BSUB;
    constexpr int NWAVES = WM * WN;
    static_assert(NSUB % NWAVES == 0, "subtile split over waves");
    constexpr int PW = NSUB / NWAVES;  // staged chunks per wave per tile
    constexpr int MT = BM / (16 * WM), NT = BN / (16 * WN);
    constexpr int BUF = NSUB * 512;
    constexpr int NBUF = DEPTH + 1;
    __shared__ bf16_t lds[NBUF * BUF];

    const int tid = threadIdx.x, lane = tid & 63, wave = tid >> 6;
    const int wm = wave / WN, wn = wave % WN;
    const int l15 = lane & 15, quad = lane >> 4;

    int bx = blockIdx.x, by = blockIdx.y;
    if constexpr (SWZ == 2) {
        // hw id -> (xcd, slot); xcd owns logical rows by ≡ xcd (mod 8), bx fastest.
        const int hwid = by * gridDim.x + bx;
        const int xcd = hwid & 7, j = hwid >> 3;
        bx = j % gridDim.x;
        by = xcd + 8 * (j / gridDim.x);
    }
    const int bm0 = by * BM, bn0 = bx * BN;

    // per-lane staging source pointers (advance by 32 elems per K-iter)
    const bf16_t* gsrc[PW];
    bf16_t* ldst[PW];
#pragma unroll
    for (int q = 0; q < PW; q++) {
        int s = wave * PW + q;
        if (s < ASUB)
            gsrc[q] = A + (size_t)(bm0 + s * 16 + l15) * K + quad * 8;
        else
            gsrc[q] = Bm + (size_t)(bn0 + (s - ASUB) * 16 + l15) * K + quad * 8;
        ldst[q] = &lds[s * 512];
    }

    f32x4 acc[MT][NT];
#pragma unroll
    for (int i = 0; i < MT; i++)
#pragma unroll
        for (int j = 0; j < NT; j++) acc[i][j] = f32x4{0.f, 0.f, 0.f, 0.f};

    auto compute = [&](int base) {
        bf16x8 af[MT], bfg[NT];
#pragma unroll
        for (int i = 0; i < MT; i++)
            af[i] = *(const bf16x8*)&lds[base + (wm * MT + i) * 512 + lane * 8];
#pragma unroll
        for (int j = 0; j < NT; j++)
            bfg[j] = *(const bf16x8*)&lds[base + (ASUB + wn * NT + j) * 512 + lane * 8];
#pragma unroll
        for (int i = 0; i < MT; i++)
#pragma unroll
            for (int j = 0; j < NT; j++)
                acc[i][j] = __builtin_amdgcn_mfma_f32_16x16x32_bf16(af[i], bfg[j], acc[i][j], 0, 0, 0);
    };

    const int nk = K / 32;  // launcher guarantees nk > DEPTH
    // prologue: tiles 0..DEPTH-1 into buffers 0..DEPTH-1
#pragma unroll
    for (int d = 0; d < DEPTH; d++)
#pragma unroll
        for (int q = 0; q < PW; q++) async16(gsrc[q] + d * 32, ldst[q] + d * BUF);

    int cb = 0;  // buffer holding tile t
    for (int t = 0; t < nk - DEPTH; t++) {
        wbar<(DEPTH - 1) * PW>();      // tile t landed everywhere; t+1.. still flying
        int ib = cb + DEPTH; if (ib >= NBUF) ib -= NBUF;
#pragma unroll
        for (int q = 0; q < PW; q++) async16(gsrc[q] + (t + DEPTH) * 32, ldst[q] + ib * BUF);
        compute(cb * BUF);
        cb++; if (cb == NBUF) cb = 0;
    }
    // tail: all remaining tiles already issued; one drain, then barrier-free compute
    wbar<0>();
    for (int t2 = 0; t2 < DEPTH; t2++) {
        compute(cb * BUF);
        cb++; if (cb == NBUF) cb = 0;
    }

// epilogue: C/D layout col=lane&15, row=quad*4+reg
#pragma unroll
    for (int j = 0; j < NT; j++) {
        const int col = bn0 + wn * (BN / WN) + j * 16 + l15;
        float bb = (EP == 2) ? 0.f : bias[col];
#pragma unroll
        for (int i = 0; i < MT; i++) {
#pragma unroll
            for (int r = 0; r < 4; r++) {
                const int row = bm0 + wm * (BM / WM) + i * 16 + quad * 4 + r;
                float x = acc[i][j][r];
                if constexpr (EP == 0) {
                    ((float*)Cout)[(size_t)row * N + col] = x + bb;
                } else if constexpr (EP == 1) {
                    ((bf16_t*)Cout)[(size_t)row * N + col] = (bf16_t)(x + bb);
                } else {
                    ((bf16_t*)Cout)[(size_t)row * N + col] = (bf16_t)fmaxf(x, 0.f);
                }
            }
        }
    }
}

// ---------------- fused gates GEMM + LSTM cell ----------------
// Block computes a 64(row b) x 32(col n) tile of hx/cx; accumulates all 4 gate slices
// of w_hh. Grid (16,16) = 256 blocks. Counted-vmcnt DEPTH=2 (3 bufs, 36 KB -> 4 blk/CU).
__global__ __launch_bounds__(256) void gates_cell(
    const bf16_t* __restrict__ hx_in, const bf16_t* __restrict__ whh,
    const float* __restrict__ vt, const float* __restrict__ wih,
    const float* __restrict__ bih, const float* __restrict__ bhh,
    float* __restrict__ cx, bf16_t* __restrict__ hx_out) {
    // chunks: 0..3 = A (64 rows of hx), 4..11 = B (4 gates x 2 halves of 32 n-cols)
    constexpr int NCH = 12, BUF = NCH * 512, PW = 3;
    constexpr int DEPTH = 2, NBUF = DEPTH + 1;
    __shared__ bf16_t lds[NBUF * BUF];
    const int tid = threadIdx.x, lane = tid & 63, wave = tid >> 6;
    const int wm = wave >> 1, wn = wave & 1;
    const int l15 = lane & 15, quad = lane >> 4;
    const int bm0 = blockIdx.y * 64, bn0 = blockIdx.x * 32;

    const bf16_t* gsrc[PW];
    bf16_t* ldst[PW];
#pragma unroll
    for (int q = 0; q < PW; q++) {
        int s = wave * PW + q;
        if (s < 4) {
            gsrc[q] = hx_in + (size_t)(bm0 + s * 16 + l15) * NH_SZ + quad * 8;
        } else {
            int sb = s - 4, gi = sb >> 1, h = sb & 1;
            gsrc[q] = whh + (size_t)(gi * NH_SZ + bn0 + h * 16 + l15) * NH_SZ + quad * 8;
        }
        ldst[q] = &lds[s * 512];
    }

    f32x4 acc[4][2];
#pragma unroll
    for (int g = 0; g < 4; g++)
#pragma unroll
        for (int i = 0; i < 2; i++) acc[g][i] = f32x4{0.f, 0.f, 0.f, 0.f};

    auto compute = [&](int base) {
        bf16x8 af[2], bg[4];
#pragma unroll
        for (int i = 0; i < 2; i++)
            af[i] = *(const bf16x8*)&lds[base + (wm * 2 + i) * 512 + lane * 8];
#pragma unroll
        for (int g = 0; g < 4; g++)
            bg[g] = *(const bf16x8*)&lds[base + (4 + g * 2 + wn) * 512 + lane * 8];
#pragma unroll
        for (int g = 0; g < 4; g++)
#pragma unroll
            for (int i = 0; i < 2; i++)
                acc[g][i] = __builtin_amdgcn_mfma_f32_16x16x32_bf16(af[i], bg[g], acc[g][i], 0, 0, 0);
    };

    constexpr int NK = NH_SZ / 32;  // 16 > DEPTH
#pragma unroll
    for (int d = 0; d < DEPTH; d++)
#pragma unroll
        for (int q = 0; q < PW; q++) async16(gsrc[q] + d * 32, ldst[q] + d * BUF);

    int cb = 0;
    for (int t = 0; t < NK - DEPTH; t++) {
        wbar<(DEPTH - 1) * PW>();
        int ib = cb + DEPTH; if (ib >= NBUF) ib -= NBUF;
#pragma unroll
        for (int q = 0; q < PW; q++) async16(gsrc[q] + (t + DEPTH) * 32, ldst[q] + ib * BUF);
        compute(cb * BUF);
        cb++; if (cb == NBUF) cb = 0;
    }
    wbar<0>();
    for (int t2 = 0; t2 < DEPTH; t2++) {
        compute(cb * BUF);
        cb++; if (cb == NBUF) cb = 0;
    }

    const int col = bn0 + wn * 16 + l15;
    float bi[4], w0[4], w1[4];
#pragma unroll
    for (int g = 0; g < 4; g++) {
        int gc = g * NH_SZ + col;
        bi[g] = bih[gc] + bhh[gc];
        w0[g] = wih[gc * 2];
        w1[g] = wih[gc * 2 + 1];
    }
#pragma unroll
    for (int i = 0; i < 2; i++) {
#pragma unroll
        for (int r = 0; r < 4; r++) {
            const int row = bm0 + wm * 32 + i * 16 + quad * 4 + r;
            float v0 = vt[row * 2], v1 = vt[row * 2 + 1];
            float xi = acc[0][i][r] + bi[0] + v0 * w0[0] + v1 * w1[0];
            float xf = acc[1][i][r] + bi[1] + v0 * w0[1] + v1 * w1[1];
            float xg = acc[2][i][r] + bi[2] + v0 * w0[2] + v1 * w1[2];
            float xo = acc[3][i][r] + bi[3] + v0 * w0[3] + v1 * w1[3];
            float ig = 1.f / (1.f + __expf(-xi));
            float fg = 1.f / (1.f + __expf(-xf));
            float gg = tanhf(xg);
            float og = 1.f / (1.f + __expf(-xo));
            int idx = (row << 9) + col;
            float c = fg * cx[idx] + ig * gg;
            cx[idx] = c;
            hx_out[idx] = (bf16_t)(og * tanhf(c));
        }
    }
}

// ---------------- host launcher ----------------
extern "C" void kernel_launch(void* const* d_in, const int* in_sizes, int n_in,
                              void* d_out, int out_size, void* d_ws, size_t ws_size,
                              hipStream_t stream) {
    const float* v    = (const float*)d_in[0];
    const float* p0   = (const float*)d_in[1];
    const float* e1w  = (const float*)d_in[2];
    const float* e1b  = (const float*)d_in[3];
    const float* e2w  = (const float*)d_in[4];
    const float* e2b  = (const float*)d_in[5];
    const float* wih  = (const float*)d_in[6];
    const float* whh  = (const float*)d_in[7];
    const float* bih  = (const float*)d_in[8];
    const float* bhh  = (const float*)d_in[9];
    const float* gw   = (const float*)d_in[10];
    const float* decw = (const float*)d_in[11];
    const float* decb = (const float*)d_in[12];
    float* out = (float*)d_out;

    size_t off = 0;
    auto take = [&](size_t bytes) {
        size_t o = off;
        off += (bytes + 255) & ~(size_t)255;
        return (void*)((char*)d_ws + o);
    };
    bf16_t* p0b   = (bf16_t*)take((size_t)B_SZ * NP_SZ * 2);
    bf16_t* e1wb  = (bf16_t*)take((size_t)NH_SZ * NP_SZ * 2);
    bf16_t* e2wb  = (bf16_t*)take((size_t)NH_SZ * NP_SZ * 2);
    bf16_t* whhb  = (bf16_t*)take((size_t)4 * NH_SZ * NH_SZ * 2);
    bf16_t* gwb   = (bf16_t*)take((size_t)NG_SZ * NH_SZ * 2);
    bf16_t* decwb = (bf16_t*)take((size_t)NP_SZ * NG_SZ * 2);
    bf16_t* hxA   = (bf16_t*)take((size_t)B_SZ * NH_SZ * 2);
    bf16_t* hxB   = (bf16_t*)take((size_t)B_SZ * NH_SZ * 2);
    float*  cxf   = (float*)take((size_t)B_SZ * NH_SZ * 4);

    // decoder chunk size: largest divisor of T that fits remaining workspace
    const size_t per_step = (size_t)B_SZ * NG_SZ * 2;  // 8 MB bf16
    int C = 1;
    for (int c : {25, 10, 5, 2, 1}) {
        if (off + (size_t)c * per_step <= ws_size) { C = c; break; }
    }
    bf16_t* gbuf = (bf16_t*)take((size_t)C * per_step);

    auto cvt = [&](const float* s, bf16_t* d, int n) {
        int n4 = n >> 2;
        cvt_f32_bf16<<<dim3((n4 + 255) / 256), dim3(256), 0, stream>>>(s, d, n4);
    };
    cvt(p0, p0b, B_SZ * NP_SZ);
    cvt(e1w, e1wb, NH_SZ * NP_SZ);
    cvt(e2w, e2wb, NH_SZ * NP_SZ);
    cvt(whh, whhb, 4 * NH_SZ * NH_SZ);
    cvt(gw, gwb, NG_SZ * NH_SZ);
    cvt(decw, decwb, NP_SZ * NG_SZ);

    // encoders: hx0 (bf16), cx0 (f32). 64x64 tiles -> 128 blocks each, depth-4.
    gemm16<64, 64, 2, 2, 4, 1, 0><<<dim3(NH_SZ / 64, B_SZ / 64), 256, 0, stream>>>(
        p0b, e1wb, e1b, hxA, B_SZ, NH_SZ, NP_SZ);
    gemm16<64, 64, 2, 2, 4, 0, 0><<<dim3(NH_SZ / 64, B_SZ / 64), 256, 0, stream>>>(
        p0b, e2wb, e2b, cxf, B_SZ, NH_SZ, NP_SZ);

    bf16_t* hin = hxA;
    bf16_t* hout = hxB;
    for (int t = 0; t < T_STEPS; t++) {
        const float* vt = v + (size_t)t * B_SZ * 2;
        // fused gates + cell: grid (NH/32, B/64) = (16,16) = 256 blocks, depth-2
        gates_cell<<<dim3(NH_SZ / 32, B_SZ / 64), 256, 0, stream>>>(
            hin, whhb, vt, wih, bih, bhh, cxf, hout);
        // g = relu(hx @ g_w^T): 128x128 tiles -> (32,8) = 256 blocks, depth-2,
        // A-affinity swizzle (gy=8 % 8 == 0)
        gemm16<128, 128, 2, 2, 2, 2, 2><<<dim3(NG_SZ / 128, B_SZ / 128), 256, 0, stream>>>(
            hout, gwb, nullptr, gbuf + (size_t)(t % C) * B_SZ * NG_SZ, B_SZ, NG_SZ, NH_SZ);
        // chunked batched decoder: 128x256 tiles, 8 waves (512 thr), depth-2
        // (72 KB LDS -> 2 blk/CU), A staged only 2x. A-affinity swizzle
        // (gy = 8C in {200,80,40,16,8}, all % 8 == 0)
        if ((t + 1) % C == 0) {
            int t0 = t + 1 - C;
            gemm16<128, 256, 2, 4, 2, 0, 2><<<dim3(NP_SZ / 256, (C * B_SZ) / 128), 512, 0, stream>>>(
                gbuf, decwb, decb, out + (size_t)t0 * B_SZ * NP_SZ, C * B_SZ, NP_SZ, NG_SZ);
        }
        // swap hx buffers
        bf16_t* tmp = hin; hin = hout; hout = tmp;
    }
}

// Round 8
// 1676.413 us; speedup vs baseline: 1.1182x; 1.0306x over previous
//
#include <hip/hip_runtime.h>
#include <hip/hip_bf16.h>

typedef __bf16 bf16_t;
typedef __bf16 bf16x4 __attribute__((ext_vector_type(4)));
typedef __bf16 bf16x8 __attribute__((ext_vector_type(8)));
typedef float f32x4 __attribute__((ext_vector_type(4)));

constexpr int T_STEPS = 50;
constexpr int B_SZ = 1024;
constexpr int NP_SZ = 512;
constexpr int NH_SZ = 512;
constexpr int NG_SZ = 4096;

// async 16B/lane global->LDS. LDS dest is wave-uniform base; HW deposits lane i at base + i*16.
__device__ __forceinline__ void async16(const bf16_t* g, bf16_t* l) {
    __builtin_amdgcn_global_load_lds((const __attribute__((address_space(1))) void*)g,
                                     (__attribute__((address_space(3))) void*)l, 16, 0, 0);
}

// Fused counted-vmcnt wait + workgroup barrier in ONE asm block with "memory" clobber.
// The builtin s_barrier is NOT a compiler memory fence: ds_reads and global_load_lds
// issues can be scheduled across it (r5 race). The memory clobber pins all memory ops
// on their side; sched_barrier(0) pins the rest.
template <int N> __device__ __forceinline__ void wbar() {
    if constexpr (N == 0)       asm volatile("s_waitcnt vmcnt(0)\n\ts_barrier" ::: "memory");
    else if constexpr (N == 2)  asm volatile("s_waitcnt vmcnt(2)\n\ts_barrier" ::: "memory");
    else if constexpr (N == 3)  asm volatile("s_waitcnt vmcnt(3)\n\ts_barrier" ::: "memory");
    else if constexpr (N == 4)  asm volatile("s_waitcnt vmcnt(4)\n\ts_barrier" ::: "memory");
    else if constexpr (N == 5)  asm volatile("s_waitcnt vmcnt(5)\n\ts_barrier" ::: "memory");
    else if constexpr (N == 6)  asm volatile("s_waitcnt vmcnt(6)\n\ts_barrier" ::: "memory");
    else if constexpr (N == 8)  asm volatile("s_waitcnt vmcnt(8)\n\ts_barrier" ::: "memory");
    else if constexpr (N == 12) asm volatile("s_waitcnt vmcnt(12)\n\ts_barrier" ::: "memory");
    else static_assert(N < 0, "add vmcnt literal");
    __builtin_amdgcn_sched_barrier(0);
}

// ---------------- fp32 -> bf16 convert ----------------
__global__ __launch_bounds__(256) void cvt_f32_bf16(const float* __restrict__ src,
                                                    bf16_t* __restrict__ dst, int n4) {
    int i = blockIdx.x * blockDim.x + threadIdx.x;
    if (i >= n4) return;
    float4 v = ((const float4*)src)[i];
    bf16x4 o;
    o[0] = (bf16_t)v.x; o[1] = (bf16_t)v.y; o[2] = (bf16_t)v.z; o[3] = (bf16_t)v.w;
    ((bf16x4*)dst)[i] = o;
}

// ---------------- counted-vmcnt depth-D GEMM: C = ep(A[M,K] @ B[N,K]^T) ----------------
// WM x WN wave grid (WM*WN waves, 64*WM*WN threads). LDS fragment order: chunk =
// 16 rows x 32 cols = 64 lanes x 16B; lane l holds rows (s*16+(l&15)), cols (l>>4)*8..
// == its MFMA fragment. Chunk->wave mapping is INTERLEAVED (s = q*NWAVES + wave) so
// every wave's per-tile staging batch mixes A (possibly cold) and B (L2-hot) chunks —
// the per-iter barrier couples all waves to the slowest, so concentrating cold loads
// in one wave serializes the block on it.
// NBUF = DEPTH+1 buffers, DEPTH tiles in flight; per-iter: wbar<(DEPTH-1)*PW> (tile t
// landed everywhere, t+1..t+D-1 flying) -> issue tile t+DEPTH -> ds_read+MFMA tile t.
// vmcnt never drains to 0 in the main loop (T4). Tail: one full drain, last DEPTH
// tiles barrier-free. Launcher guarantees nk > DEPTH.
// SWZ: 0 = none | 2 = A-panel XCD affinity (hw XCD owns logical rows by%8==xcd; needs
//      gridDim.y % 8 == 0) so the gridDim.x blocks sharing an A-panel hit one L2.
// EP: 0 = +bias f32 out | 1 = +bias bf16 out | 2 = relu bf16 out
template <int BM, int BN, int WM, int WN, int DEPTH, int EP, int SWZ>
__global__ __launch_bounds__(WM * WN * 64) void gemm16(const bf16_t* __restrict__ A,
                                                       const bf16_t* __restrict__ Bm,
                                                       const float* __restrict__ bias,
                                                       void* __restrict__ Cout, int M, int N, int K) {
    constexpr int ASUB = BM / 16, BSUB = BN / 16, NSUB = ASUB + BSUB;
    constexpr int NWAVES = WM * WN;
    static_assert(NSUB % NWAVES == 0, "subtile split over waves");
    constexpr int PW = NSUB / NWAVES;  // staged chunks per wave per tile
    constexpr int MT = BM / (16 * WM), NT = BN / (16 * WN);
    constexpr int BUF = NSUB * 512;
    constexpr int NBUF = DEPTH + 1;
    __shared__ bf16_t lds[NBUF * BUF];

    const int tid = threadIdx.x, lane = tid & 63, wave = tid >> 6;
    const int wm = wave / WN, wn = wave % WN;
    const int l15 = lane & 15, quad = lane >> 4;

    int bx = blockIdx.x, by = blockIdx.y;
    if constexpr (SWZ == 2) {
        // hw id -> (xcd, slot); xcd owns logical rows by ≡ xcd (mod 8), bx fastest.
        const int hwid = by * gridDim.x + bx;
        const int xcd = hwid & 7, j = hwid >> 3;
        bx = j % gridDim.x;
        by = xcd + 8 * (j / gridDim.x);
    }
    const int bm0 = by * BM, bn0 = bx * BN;

    // per-lane staging source pointers (advance by 32 elems per K-iter)
    const bf16_t* gsrc[PW];
    bf16_t* ldst[PW];
#pragma unroll
    for (int q = 0; q < PW; q++) {
        int s = q * NWAVES + wave;  // interleaved: each wave gets A- and B-chunks
        if (s < ASUB)
            gsrc[q] = A + (size_t)(bm0 + s * 16 + l15) * K + quad * 8;
        else
            gsrc[q] = Bm + (size_t)(bn0 + (s - ASUB) * 16 + l15) * K + quad * 8;
        ldst[q] = &lds[s * 512];
    }

    f32x4 acc[MT][NT];
#pragma unroll
    for (int i = 0; i < MT; i++)
#pragma unroll
        for (int j = 0; j < NT; j++) acc[i][j] = f32x4{0.f, 0.f, 0.f, 0.f};

    auto compute = [&](int base) {
        bf16x8 af[MT], bfg[NT];
#pragma unroll
        for (int i = 0; i < MT; i++)
            af[i] = *(const bf16x8*)&lds[base + (wm * MT + i) * 512 + lane * 8];
#pragma unroll
        for (int j = 0; j < NT; j++)
            bfg[j] = *(const bf16x8*)&lds[base + (ASUB + wn * NT + j) * 512 + lane * 8];
#pragma unroll
        for (int i = 0; i < MT; i++)
#pragma unroll
            for (int j = 0; j < NT; j++)
                acc[i][j] = __builtin_amdgcn_mfma_f32_16x16x32_bf16(af[i], bfg[j], acc[i][j], 0, 0, 0);
    };

    const int nk = K / 32;  // launcher guarantees nk > DEPTH
    // prologue: tiles 0..DEPTH-1 into buffers 0..DEPTH-1
#pragma unroll
    for (int d = 0; d < DEPTH; d++)
#pragma unroll
        for (int q = 0; q < PW; q++) async16(gsrc[q] + d * 32, ldst[q] + d * BUF);

    int cb = 0;  // buffer holding tile t
    for (int t = 0; t < nk - DEPTH; t++) {
        wbar<(DEPTH - 1) * PW>();      // tile t landed everywhere; t+1.. still flying
        int ib = cb + DEPTH; if (ib >= NBUF) ib -= NBUF;
#pragma unroll
        for (int q = 0; q < PW; q++) async16(gsrc[q] + (t + DEPTH) * 32, ldst[q] + ib * BUF);
        compute(cb * BUF);
        cb++; if (cb == NBUF) cb = 0;
    }
    // tail: all remaining tiles already issued; one drain, then barrier-free compute
    wbar<0>();
    for (int t2 = 0; t2 < DEPTH; t2++) {
        compute(cb * BUF);
        cb++; if (cb == NBUF) cb = 0;
    }

// epilogue: C/D layout col=lane&15, row=quad*4+reg
#pragma unroll
    for (int j = 0; j < NT; j++) {
        const int col = bn0 + wn * (BN / WN) + j * 16 + l15;
        float bb = (EP == 2) ? 0.f : bias[col];
#pragma unroll
        for (int i = 0; i < MT; i++) {
#pragma unroll
            for (int r = 0; r < 4; r++) {
                const int row = bm0 + wm * (BM / WM) + i * 16 + quad * 4 + r;
                float x = acc[i][j][r];
                if constexpr (EP == 0) {
                    ((float*)Cout)[(size_t)row * N + col] = x + bb;
                } else if constexpr (EP == 1) {
                    ((bf16_t*)Cout)[(size_t)row * N + col] = (bf16_t)(x + bb);
                } else {
                    ((bf16_t*)Cout)[(size_t)row * N + col] = (bf16_t)fmaxf(x, 0.f);
                }
            }
        }
    }
}

// ---------------- fused gates GEMM + LSTM cell ----------------
// Block computes a 64(row b) x 32(col n) tile of hx/cx; accumulates all 4 gate slices
// of w_hh. Grid (16,16) = 256 blocks. Counted-vmcnt DEPTH=2 (3 bufs, 36 KB -> 4 blk/CU).
// Interleaved chunk->wave mapping (1 A + 2 B per wave).
__global__ __launch_bounds__(256) void gates_cell(
    const bf16_t* __restrict__ hx_in, const bf16_t* __restrict__ whh,
    const float* __restrict__ vt, const float* __restrict__ wih,
    const float* __restrict__ bih, const float* __restrict__ bhh,
    float* __restrict__ cx, bf16_t* __restrict__ hx_out) {
    // chunks: 0..3 = A (64 rows of hx), 4..11 = B (4 gates x 2 halves of 32 n-cols)
    constexpr int NCH = 12, BUF = NCH * 512, PW = 3;
    constexpr int DEPTH = 2, NBUF = DEPTH + 1;
    __shared__ bf16_t lds[NBUF * BUF];
    const int tid = threadIdx.x, lane = tid & 63, wave = tid >> 6;
    const int wm = wave >> 1, wn = wave & 1;
    const int l15 = lane & 15, quad = lane >> 4;
    const int bm0 = blockIdx.y * 64, bn0 = blockIdx.x * 32;

    const bf16_t* gsrc[PW];
    bf16_t* ldst[PW];
#pragma unroll
    for (int q = 0; q < PW; q++) {
        int s = q * 4 + wave;  // interleaved
        if (s < 4) {
            gsrc[q] = hx_in + (size_t)(bm0 + s * 16 + l15) * NH_SZ + quad * 8;
        } else {
            int sb = s - 4, gi = sb >> 1, h = sb & 1;
            gsrc[q] = whh + (size_t)(gi * NH_SZ + bn0 + h * 16 + l15) * NH_SZ + quad * 8;
        }
        ldst[q] = &lds[s * 512];
    }

    f32x4 acc[4][2];
#pragma unroll
    for (int g = 0; g < 4; g++)
#pragma unroll
        for (int i = 0; i < 2; i++) acc[g][i] = f32x4{0.f, 0.f, 0.f, 0.f};

    auto compute = [&](int base) {
        bf16x8 af[2], bg[4];
#pragma unroll
        for (int i = 0; i < 2; i++)
            af[i] = *(const bf16x8*)&lds[base + (wm * 2 + i) * 512 + lane * 8];
#pragma unroll
        for (int g = 0; g < 4; g++)
            bg[g] = *(const bf16x8*)&lds[base + (4 + g * 2 + wn) * 512 + lane * 8];
#pragma unroll
        for (int g = 0; g < 4; g++)
#pragma unroll
            for (int i = 0; i < 2; i++)
                acc[g][i] = __builtin_amdgcn_mfma_f32_16x16x32_bf16(af[i], bg[g], acc[g][i], 0, 0, 0);
    };

    constexpr int NK = NH_SZ / 32;  // 16 > DEPTH
#pragma unroll
    for (int d = 0; d < DEPTH; d++)
#pragma unroll
        for (int q = 0; q < PW; q++) async16(gsrc[q] + d * 32, ldst[q] + d * BUF);

    int cb = 0;
    for (int t = 0; t < NK - DEPTH; t++) {
        wbar<(DEPTH - 1) * PW>();
        int ib = cb + DEPTH; if (ib >= NBUF) ib -= NBUF;
#pragma unroll
        for (int q = 0; q < PW; q++) async16(gsrc[q] + (t + DEPTH) * 32, ldst[q] + ib * BUF);
        compute(cb * BUF);
        cb++; if (cb == NBUF) cb = 0;
    }
    wbar<0>();
    for (int t2 = 0; t2 < DEPTH; t2++) {
        compute(cb * BUF);
        cb++; if (cb == NBUF) cb = 0;
    }

    const int col = bn0 + wn * 16 + l15;
    float bi[4], w0[4], w1[4];
#pragma unroll
    for (int g = 0; g < 4; g++) {
        int gc = g * NH_SZ + col;
        bi[g] = bih[gc] + bhh[gc];
        w0[g] = wih[gc * 2];
        w1[g] = wih[gc * 2 + 1];
    }
#pragma unroll
    for (int i = 0; i < 2; i++) {
#pragma unroll
        for (int r = 0; r < 4; r++) {
            const int row = bm0 + wm * 32 + i * 16 + quad * 4 + r;
            float v0 = vt[row * 2], v1 = vt[row * 2 + 1];
            float xi = acc[0][i][r] + bi[0] + v0 * w0[0] + v1 * w1[0];
            float xf = acc[1][i][r] + bi[1] + v0 * w0[1] + v1 * w1[1];
            float xg = acc[2][i][r] + bi[2] + v0 * w0[2] + v1 * w1[2];
            float xo = acc[3][i][r] + bi[3] + v0 * w0[3] + v1 * w1[3];
            float ig = 1.f / (1.f + __expf(-xi));
            float fg = 1.f / (1.f + __expf(-xf));
            float gg = tanhf(xg);
            float og = 1.f / (1.f + __expf(-xo));
            int idx = (row << 9) + col;
            float c = fg * cx[idx] + ig * gg;
            cx[idx] = c;
            hx_out[idx] = (bf16_t)(og * tanhf(c));
        }
    }
}

// ---------------- host launcher ----------------
extern "C" void kernel_launch(void* const* d_in, const int* in_sizes, int n_in,
                              void* d_out, int out_size, void* d_ws, size_t ws_size,
                              hipStream_t stream) {
    const float* v    = (const float*)d_in[0];
    const float* p0   = (const float*)d_in[1];
    const float* e1w  = (const float*)d_in[2];
    const float* e1b  = (const float*)d_in[3];
    const float* e2w  = (const float*)d_in[4];
    const float* e2b  = (const float*)d_in[5];
    const float* wih  = (const float*)d_in[6];
    const float* whh  = (const float*)d_in[7];
    const float* bih  = (const float*)d_in[8];
    const float* bhh  = (const float*)d_in[9];
    const float* gw   = (const float*)d_in[10];
    const float* decw = (const float*)d_in[11];
    const float* decb = (const float*)d_in[12];
    float* out = (float*)d_out;

    size_t off = 0;
    auto take = [&](size_t bytes) {
        size_t o = off;
        off += (bytes + 255) & ~(size_t)255;
        return (void*)((char*)d_ws + o);
    };
    bf16_t* p0b   = (bf16_t*)take((size_t)B_SZ * NP_SZ * 2);
    bf16_t* e1wb  = (bf16_t*)take((size_t)NH_SZ * NP_SZ * 2);
    bf16_t* e2wb  = (bf16_t*)take((size_t)NH_SZ * NP_SZ * 2);
    bf16_t* whhb  = (bf16_t*)take((size_t)4 * NH_SZ * NH_SZ * 2);
    bf16_t* gwb   = (bf16_t*)take((size_t)NG_SZ * NH_SZ * 2);
    bf16_t* decwb = (bf16_t*)take((size_t)NP_SZ * NG_SZ * 2);
    bf16_t* hxA   = (bf16_t*)take((size_t)B_SZ * NH_SZ * 2);
    bf16_t* hxB   = (bf16_t*)take((size_t)B_SZ * NH_SZ * 2);
    float*  cxf   = (float*)take((size_t)B_SZ * NH_SZ * 4);

    // decoder chunk size: largest divisor of T that fits remaining workspace
    const size_t per_step = (size_t)B_SZ * NG_SZ * 2;  // 8 MB bf16
    int C = 1;
    for (int c : {25, 10, 5, 2, 1}) {
        if (off + (size_t)c * per_step <= ws_size) { C = c; break; }
    }
    bf16_t* gbuf = (bf16_t*)take((size_t)C * per_step);

    auto cvt = [&](const float* s, bf16_t* d, int n) {
        int n4 = n >> 2;
        cvt_f32_bf16<<<dim3((n4 + 255) / 256), dim3(256), 0, stream>>>(s, d, n4);
    };
    cvt(p0, p0b, B_SZ * NP_SZ);
    cvt(e1w, e1wb, NH_SZ * NP_SZ);
    cvt(e2w, e2wb, NH_SZ * NP_SZ);
    cvt(whh, whhb, 4 * NH_SZ * NH_SZ);
    cvt(gw, gwb, NG_SZ * NH_SZ);
    cvt(decw, decwb, NP_SZ * NG_SZ);

    // encoders: hx0 (bf16), cx0 (f32). 64x64 tiles -> 128 blocks each, depth-4.
    gemm16<64, 64, 2, 2, 4, 1, 0><<<dim3(NH_SZ / 64, B_SZ / 64), 256, 0, stream>>>(
        p0b, e1wb, e1b, hxA, B_SZ, NH_SZ, NP_SZ);
    gemm16<64, 64, 2, 2, 4, 0, 0><<<dim3(NH_SZ / 64, B_SZ / 64), 256, 0, stream>>>(
        p0b, e2wb, e2b, cxf, B_SZ, NH_SZ, NP_SZ);

    bf16_t* hin = hxA;
    bf16_t* hout = hxB;
    for (int t = 0; t < T_STEPS; t++) {
        const float* vt = v + (size_t)t * B_SZ * 2;
        // fused gates + cell: grid (NH/32, B/64) = (16,16) = 256 blocks, depth-2
        gates_cell<<<dim3(NH_SZ / 32, B_SZ / 64), 256, 0, stream>>>(
            hin, whhb, vt, wih, bih, bhh, cxf, hout);
        // g = relu(hx @ g_w^T): 128x128 tiles, 8 waves, depth-4 -> (32,8) = 256 blocks,
        // A-affinity swizzle (gy=8 % 8 == 0). PW=2: every wave stages 1 A + 1 B chunk.
        gemm16<128, 128, 2, 4, 4, 2, 2><<<dim3(NG_SZ / 128, B_SZ / 128), 512, 0, stream>>>(
            hout, gwb, nullptr, gbuf + (size_t)(t % C) * B_SZ * NG_SZ, B_SZ, NG_SZ, NH_SZ);
        // chunked batched decoder: 128x512 tiles, 8 waves, depth-2 (120 KB LDS),
        // grid (1, 200): A (cold gbuf) staged exactly ONCE -> staged volume 610 MB.
        // PW=5: every wave stages exactly 1 A (cold) + 4 B (L2-hot) chunks.
        if ((t + 1) % C == 0) {
            int t0 = t + 1 - C;
            gemm16<128, 512, 2, 4, 2, 0, 0><<<dim3(NP_SZ / 512, (C * B_SZ) / 128), 512, 0, stream>>>(
                gbuf, decwb, decb, out + (size_t)t0 * B_SZ * NP_SZ, C * B_SZ, NP_SZ, NG_SZ);
        }
        // swap hx buffers
        bf16_t* tmp = hin; hin = hout; hout = tmp;
    }
}

// Round 9
// 1542.771 us; speedup vs baseline: 1.2151x; 1.0866x over previous
//
#include <hip/hip_runtime.h>
#include <hip/hip_bf16.h>

typedef __bf16 bf16_t;
typedef __bf16 bf16x4 __attribute__((ext_vector_type(4)));
typedef __bf16 bf16x8 __attribute__((ext_vector_type(8)));
typedef float f32x4 __attribute__((ext_vector_type(4)));

constexpr int T_STEPS = 50;
constexpr int B_SZ = 1024;
constexpr int NP_SZ = 512;
constexpr int NH_SZ = 512;
constexpr int NG_SZ = 4096;

// async 16B/lane global->LDS. LDS dest is wave-uniform base; HW deposits lane i at base + i*16.
__device__ __forceinline__ void async16(const bf16_t* g, bf16_t* l) {
    __builtin_amdgcn_global_load_lds((const __attribute__((address_space(1))) void*)g,
                                     (__attribute__((address_space(3))) void*)l, 16, 0, 0);
}

// Fused counted-vmcnt wait + workgroup barrier in ONE asm block with "memory" clobber.
// The builtin s_barrier is NOT a compiler memory fence (r5 race). The memory clobber
// pins all memory ops on their side; sched_barrier(0) pins the rest.
template <int N> __device__ __forceinline__ void wbar() {
    if constexpr (N == 0)       asm volatile("s_waitcnt vmcnt(0)\n\ts_barrier" ::: "memory");
    else if constexpr (N == 2)  asm volatile("s_waitcnt vmcnt(2)\n\ts_barrier" ::: "memory");
    else if constexpr (N == 3)  asm volatile("s_waitcnt vmcnt(3)\n\ts_barrier" ::: "memory");
    else if constexpr (N == 4)  asm volatile("s_waitcnt vmcnt(4)\n\ts_barrier" ::: "memory");
    else if constexpr (N == 6)  asm volatile("s_waitcnt vmcnt(6)\n\ts_barrier" ::: "memory");
    else if constexpr (N == 8)  asm volatile("s_waitcnt vmcnt(8)\n\ts_barrier" ::: "memory");
    else static_assert(N < 0, "add vmcnt literal");
    __builtin_amdgcn_sched_barrier(0);
}

// ---------------- fp32 -> bf16 convert ----------------
__global__ __launch_bounds__(256) void cvt_f32_bf16(const float* __restrict__ src,
                                                    bf16_t* __restrict__ dst, int n4) {
    int i = blockIdx.x * blockDim.x + threadIdx.x;
    if (i >= n4) return;
    float4 v = ((const float4*)src)[i];
    bf16x4 o;
    o[0] = (bf16_t)v.x; o[1] = (bf16_t)v.y; o[2] = (bf16_t)v.z; o[3] = (bf16_t)v.w;
    ((bf16x4*)dst)[i] = o;
}

// ---------------- counted-vmcnt depth-D GEMM template (encoders + decoder) ----------------
// WM x WN wave grid. LDS fragment order: chunk = 16 rows x 32 cols = 64 lanes x 16B;
// lane l holds rows (s*16+(l&15)), cols (l>>4)*8.. == its MFMA fragment. Interleaved
// chunk->wave mapping (s = q*NWAVES + wave) balances cold/hot staging across waves.
// DEPTH tiles in flight, NBUF=DEPTH+1; per-iter: wbar<(DEPTH-1)*PW> -> issue t+DEPTH
// -> ds_read+MFMA tile t. vmcnt never drains to 0 in the main loop.
// EP: 0 = +bias f32 out | 1 = +bias bf16 out | 2 = relu bf16 out
template <int BM, int BN, int WM, int WN, int DEPTH, int EP>
__global__ __launch_bounds__(WM * WN * 64) void gemm16(const bf16_t* __restrict__ A,
                                                       const bf16_t* __restrict__ Bm,
                                                       const float* __restrict__ bias,
                                                       void* __restrict__ Cout, int M, int N, int K) {
    constexpr int ASUB = BM / 16, BSUB = BN / 16, NSUB = ASUB + BSUB;
    constexpr int NWAVES = WM * WN;
    static_assert(NSUB % NWAVES == 0, "subtile split over waves");
    constexpr int PW = NSUB / NWAVES;
    constexpr int MT = BM / (16 * WM), NT = BN / (16 * WN);
    constexpr int BUF = NSUB * 512;
    constexpr int NBUF = DEPTH + 1;
    __shared__ bf16_t lds[NBUF * BUF];

    const int tid = threadIdx.x, lane = tid & 63, wave = tid >> 6;
    const int wm = wave / WN, wn = wave % WN;
    const int l15 = lane & 15, quad = lane >> 4;
    const int bm0 = blockIdx.y * BM, bn0 = blockIdx.x * BN;

    const bf16_t* gsrc[PW];
    bf16_t* ldst[PW];
#pragma unroll
    for (int q = 0; q < PW; q++) {
        int s = q * NWAVES + wave;
        if (s < ASUB)
            gsrc[q] = A + (size_t)(bm0 + s * 16 + l15) * K + quad * 8;
        else
            gsrc[q] = Bm + (size_t)(bn0 + (s - ASUB) * 16 + l15) * K + quad * 8;
        ldst[q] = &lds[s * 512];
    }

    f32x4 acc[MT][NT];
#pragma unroll
    for (int i = 0; i < MT; i++)
#pragma unroll
        for (int j = 0; j < NT; j++) acc[i][j] = f32x4{0.f, 0.f, 0.f, 0.f};

    auto compute = [&](int base) {
        bf16x8 af[MT], bfg[NT];
#pragma unroll
        for (int i = 0; i < MT; i++)
            af[i] = *(const bf16x8*)&lds[base + (wm * MT + i) * 512 + lane * 8];
#pragma unroll
        for (int j = 0; j < NT; j++)
            bfg[j] = *(const bf16x8*)&lds[base + (ASUB + wn * NT + j) * 512 + lane * 8];
#pragma unroll
        for (int i = 0; i < MT; i++)
#pragma unroll
            for (int j = 0; j < NT; j++)
                acc[i][j] = __builtin_amdgcn_mfma_f32_16x16x32_bf16(af[i], bfg[j], acc[i][j], 0, 0, 0);
    };

    const int nk = K / 32;  // launcher guarantees nk > DEPTH
#pragma unroll
    for (int d = 0; d < DEPTH; d++)
#pragma unroll
        for (int q = 0; q < PW; q++) async16(gsrc[q] + d * 32, ldst[q] + d * BUF);

    int cb = 0;
    for (int t = 0; t < nk - DEPTH; t++) {
        wbar<(DEPTH - 1) * PW>();
        int ib = cb + DEPTH; if (ib >= NBUF) ib -= NBUF;
#pragma unroll
        for (int q = 0; q < PW; q++) async16(gsrc[q] + (t + DEPTH) * 32, ldst[q] + ib * BUF);
        compute(cb * BUF);
        cb++; if (cb == NBUF) cb = 0;
    }
    wbar<0>();
    for (int t2 = 0; t2 < DEPTH; t2++) {
        compute(cb * BUF);
        cb++; if (cb == NBUF) cb = 0;
    }

#pragma unroll
    for (int j = 0; j < NT; j++) {
        const int col = bn0 + wn * (BN / WN) + j * 16 + l15;
        float bb = (EP == 2) ? 0.f : bias[col];
#pragma unroll
        for (int i = 0; i < MT; i++) {
#pragma unroll
            for (int r = 0; r < 4; r++) {
                const int row = bm0 + wm * (BM / WM) + i * 16 + quad * 4 + r;
                float x = acc[i][j][r];
                if constexpr (EP == 0) {
                    ((float*)Cout)[(size_t)row * N + col] = x + bb;
                } else if constexpr (EP == 1) {
                    ((bf16_t*)Cout)[(size_t)row * N + col] = (bf16_t)(x + bb);
                } else {
                    ((bf16_t*)Cout)[(size_t)row * N + col] = (bf16_t)fmaxf(x, 0.f);
                }
            }
        }
    }
}

// ================= per-step bodies (512 threads, 8 waves, 48 KB LDS each) =================
constexpr int STEP_LDS = 3 * 16 * 512;  // 3 buffers x 16 chunks x 512 bf16 = 48 KB

// ---- g-GEMM body: g = relu(hx @ gw^T). 128x128 tile, WM=2 WN=4, DEPTH=2, K=512.
// grid 32 x 8 (bx = n-tile, by = m-tile). Staging: wave stages 1 A + 1 B chunk.
__device__ __forceinline__ void g_body(const bf16_t* __restrict__ A, const bf16_t* __restrict__ Bm,
                                       bf16_t* __restrict__ Cout, bf16_t* lds, int bx, int by) {
    constexpr int ASUB = 8, NSUB = 16, PW = 2, MT = 4, NT = 2, BUF = NSUB * 512, DEPTH = 2, NBUF = 3;
    const int tid = threadIdx.x, lane = tid & 63, wave = tid >> 6;
    const int wm = wave / 4, wn = wave % 4;
    const int l15 = lane & 15, quad = lane >> 4;
    const int bm0 = by * 128, bn0 = bx * 128;

    const bf16_t* gsrc[PW];
    bf16_t* ldst[PW];
#pragma unroll
    for (int q = 0; q < PW; q++) {
        int s = q * 8 + wave;
        if (s < ASUB)
            gsrc[q] = A + (size_t)(bm0 + s * 16 + l15) * NH_SZ + quad * 8;
        else
            gsrc[q] = Bm + (size_t)(bn0 + (s - ASUB) * 16 + l15) * NH_SZ + quad * 8;
        ldst[q] = &lds[s * 512];
    }

    f32x4 acc[MT][NT];
#pragma unroll
    for (int i = 0; i < MT; i++)
#pragma unroll
        for (int j = 0; j < NT; j++) acc[i][j] = f32x4{0.f, 0.f, 0.f, 0.f};

    auto compute = [&](int base) {
        bf16x8 af[MT], bfg[NT];
#pragma unroll
        for (int i = 0; i < MT; i++)
            af[i] = *(const bf16x8*)&lds[base + (wm * MT + i) * 512 + lane * 8];
#pragma unroll
        for (int j = 0; j < NT; j++)
            bfg[j] = *(const bf16x8*)&lds[base + (ASUB + wn * NT + j) * 512 + lane * 8];
#pragma unroll
        for (int i = 0; i < MT; i++)
#pragma unroll
            for (int j = 0; j < NT; j++)
                acc[i][j] = __builtin_amdgcn_mfma_f32_16x16x32_bf16(af[i], bfg[j], acc[i][j], 0, 0, 0);
    };

    constexpr int NK = NH_SZ / 32;  // 16
#pragma unroll
    for (int d = 0; d < DEPTH; d++)
#pragma unroll
        for (int q = 0; q < PW; q++) async16(gsrc[q] + d * 32, ldst[q] + d * BUF);

    int cb = 0;
    for (int t = 0; t < NK - DEPTH; t++) {
        wbar<(DEPTH - 1) * PW>();
        int ib = cb + DEPTH; if (ib >= NBUF) ib -= NBUF;
#pragma unroll
        for (int q = 0; q < PW; q++) async16(gsrc[q] + (t + DEPTH) * 32, ldst[q] + ib * BUF);
        compute(cb * BUF);
        cb++; if (cb == NBUF) cb = 0;
    }
    wbar<0>();
    for (int t2 = 0; t2 < DEPTH; t2++) {
        compute(cb * BUF);
        cb++; if (cb == NBUF) cb = 0;
    }

#pragma unroll
    for (int j = 0; j < NT; j++) {
        const int col = bn0 + wn * 32 + j * 16 + l15;
#pragma unroll
        for (int i = 0; i < MT; i++) {
#pragma unroll
            for (int r = 0; r < 4; r++) {
                const int row = bm0 + wm * 64 + i * 16 + quad * 4 + r;
                Cout[(size_t)row * NG_SZ + col] = (bf16_t)fmaxf(acc[i][j][r], 0.f);
            }
        }
    }
}

// ---- gates+cell body: 128(row b) x 32(col n) tile, 8 waves (wm=wave>>1 row-group of 32,
// wn=wave&1 col-half of 16), DEPTH=2, K=512. grid 16 x 8. Wave stages 1 A + 1 B chunk.
__device__ __forceinline__ void gates_body(const bf16_t* __restrict__ hx_in,
                                           const bf16_t* __restrict__ whh,
                                           const float* __restrict__ vt, const float* __restrict__ wih,
                                           const float* __restrict__ bih, const float* __restrict__ bhh,
                                           float* __restrict__ cx, bf16_t* __restrict__ hx_out,
                                           bf16_t* lds, int bx, int by) {
    constexpr int NSUB = 16, PW = 2, BUF = NSUB * 512, DEPTH = 2, NBUF = 3;
    const int tid = threadIdx.x, lane = tid & 63, wave = tid >> 6;
    const int wm = wave >> 1, wn = wave & 1;
    const int l15 = lane & 15, quad = lane >> 4;
    const int bm0 = by * 128, bn0 = bx * 32;

    // chunks: 0..7 = A (128 rows of hx), 8..15 = B (gate=(s-8)>>1, half=(s-8)&1)
    const bf16_t* gsrc[PW];
    bf16_t* ldst[PW];
#pragma unroll
    for (int q = 0; q < PW; q++) {
        int s = q * 8 + wave;
        if (s < 8) {
            gsrc[q] = hx_in + (size_t)(bm0 + s * 16 + l15) * NH_SZ + quad * 8;
        } else {
            int sb = s - 8, gi = sb >> 1, h = sb & 1;
            gsrc[q] = whh + (size_t)(gi * NH_SZ + bn0 + h * 16 + l15) * NH_SZ + quad * 8;
        }
        ldst[q] = &lds[s * 512];
    }

    f32x4 acc[4][2];
#pragma unroll
    for (int g = 0; g < 4; g++)
#pragma unroll
        for (int i = 0; i < 2; i++) acc[g][i] = f32x4{0.f, 0.f, 0.f, 0.f};

    auto compute = [&](int base) {
        bf16x8 af[2], bg[4];
#pragma unroll
        for (int i = 0; i < 2; i++)
            af[i] = *(const bf16x8*)&lds[base + (wm * 2 + i) * 512 + lane * 8];
#pragma unroll
        for (int g = 0; g < 4; g++)
            bg[g] = *(const bf16x8*)&lds[base + (8 + g * 2 + wn) * 512 + lane * 8];
#pragma unroll
        for (int g = 0; g < 4; g++)
#pragma unroll
            for (int i = 0; i < 2; i++)
                acc[g][i] = __builtin_amdgcn_mfma_f32_16x16x32_bf16(af[i], bg[g], acc[g][i], 0, 0, 0);
    };

    constexpr int NK = NH_SZ / 32;  // 16
#pragma unroll
    for (int d = 0; d < DEPTH; d++)
#pragma unroll
        for (int q = 0; q < PW; q++) async16(gsrc[q] + d * 32, ldst[q] + d * BUF);

    int cb = 0;
    for (int t = 0; t < NK - DEPTH; t++) {
        wbar<(DEPTH - 1) * PW>();
        int ib = cb + DEPTH; if (ib >= NBUF) ib -= NBUF;
#pragma unroll
        for (int q = 0; q < PW; q++) async16(gsrc[q] + (t + DEPTH) * 32, ldst[q] + ib * BUF);
        compute(cb * BUF);
        cb++; if (cb == NBUF) cb = 0;
    }
    wbar<0>();
    for (int t2 = 0; t2 < DEPTH; t2++) {
        compute(cb * BUF);
        cb++; if (cb == NBUF) cb = 0;
    }

    const int col = bn0 + wn * 16 + l15;
    float bi[4], w0[4], w1[4];
#pragma unroll
    for (int g = 0; g < 4; g++) {
        int gc = g * NH_SZ + col;
        bi[g] = bih[gc] + bhh[gc];
        w0[g] = wih[gc * 2];
        w1[g] = wih[gc * 2 + 1];
    }
#pragma unroll
    for (int i = 0; i < 2; i++) {
#pragma unroll
        for (int r = 0; r < 4; r++) {
            const int row = bm0 + wm * 32 + i * 16 + quad * 4 + r;
            float v0 = vt[row * 2], v1 = vt[row * 2 + 1];
            float xi = acc[0][i][r] + bi[0] + v0 * w0[0] + v1 * w1[0];
            float xf = acc[1][i][r] + bi[1] + v0 * w0[1] + v1 * w1[1];
            float xg = acc[2][i][r] + bi[2] + v0 * w0[2] + v1 * w1[2];
            float xo = acc[3][i][r] + bi[3] + v0 * w0[3] + v1 * w1[3];
            float ig = 1.f / (1.f + __expf(-xi));
            float fg = 1.f / (1.f + __expf(-xf));
            float gg = tanhf(xg);
            float og = 1.f / (1.f + __expf(-xo));
            int idx = (row << 9) + col;
            float c = fg * cx[idx] + ig * gg;
            cx[idx] = c;
            hx_out[idx] = (bf16_t)(og * tanhf(c));
        }
    }
}

// ---- standalone wrappers + fused kernel ----
__global__ __launch_bounds__(512) void gates_only(const bf16_t* hx_in, const bf16_t* whh,
                                                  const float* vt, const float* wih,
                                                  const float* bih, const float* bhh,
                                                  float* cx, bf16_t* hx_out) {
    __shared__ bf16_t lds[STEP_LDS];
    gates_body(hx_in, whh, vt, wih, bih, bhh, cx, hx_out, lds, blockIdx.x, blockIdx.y);
}

__global__ __launch_bounds__(512) void g_only(const bf16_t* hx, const bf16_t* gw, bf16_t* gout) {
    __shared__ bf16_t lds[STEP_LDS];
    g_body(hx, gw, gout, lds, blockIdx.x & 31, blockIdx.x >> 5);
}

// blocks 0..255: g-GEMM(t) (grid 32x8); blocks 256..383: gates(t+1) (grid 16x8).
// Both halves read hx(t+1); gates writes cx and hx(t+2) which g never touches.
__global__ __launch_bounds__(512) void fused_step(const bf16_t* hx, const bf16_t* gw, bf16_t* gout,
                                                  const bf16_t* whh, const float* vt_next,
                                                  const float* wih, const float* bih,
                                                  const float* bhh, float* cx, bf16_t* hx_next) {
    __shared__ bf16_t lds[STEP_LDS];
    const int id = blockIdx.x;
    if (id < 256) {
        g_body(hx, gw, gout, lds, id & 31, id >> 5);
    } else {
        const int j = id - 256;
        gates_body(hx, whh, vt_next, wih, bih, bhh, cx, hx_next, lds, j & 15, j >> 4);
    }
}

// ---------------- host launcher ----------------
extern "C" void kernel_launch(void* const* d_in, const int* in_sizes, int n_in,
                              void* d_out, int out_size, void* d_ws, size_t ws_size,
                              hipStream_t stream) {
    const float* v    = (const float*)d_in[0];
    const float* p0   = (const float*)d_in[1];
    const float* e1w  = (const float*)d_in[2];
    const float* e1b  = (const float*)d_in[3];
    const float* e2w  = (const float*)d_in[4];
    const float* e2b  = (const float*)d_in[5];
    const float* wih  = (const float*)d_in[6];
    const float* whh  = (const float*)d_in[7];
    const float* bih  = (const float*)d_in[8];
    const float* bhh  = (const float*)d_in[9];
    const float* gw   = (const float*)d_in[10];
    const float* decw = (const float*)d_in[11];
    const float* decb = (const float*)d_in[12];
    float* out = (float*)d_out;

    size_t off = 0;
    auto take = [&](size_t bytes) {
        size_t o = off;
        off += (bytes + 255) & ~(size_t)255;
        return (void*)((char*)d_ws + o);
    };
    bf16_t* p0b   = (bf16_t*)take((size_t)B_SZ * NP_SZ * 2);
    bf16_t* e1wb  = (bf16_t*)take((size_t)NH_SZ * NP_SZ * 2);
    bf16_t* e2wb  = (bf16_t*)take((size_t)NH_SZ * NP_SZ * 2);
    bf16_t* whhb  = (bf16_t*)take((size_t)4 * NH_SZ * NH_SZ * 2);
    bf16_t* gwb   = (bf16_t*)take((size_t)NG_SZ * NH_SZ * 2);
    bf16_t* decwb = (bf16_t*)take((size_t)NP_SZ * NG_SZ * 2);
    bf16_t* hxA   = (bf16_t*)take((size_t)B_SZ * NH_SZ * 2);
    bf16_t* hxB   = (bf16_t*)take((size_t)B_SZ * NH_SZ * 2);
    float*  cxf   = (float*)take((size_t)B_SZ * NH_SZ * 4);

    // decoder chunk size: largest divisor of T that fits remaining workspace
    const size_t per_step = (size_t)B_SZ * NG_SZ * 2;  // 8 MB bf16
    int C = 1;
    for (int c : {25, 10, 5, 2, 1}) {
        if (off + (size_t)c * per_step <= ws_size) { C = c; break; }
    }
    bf16_t* gbuf = (bf16_t*)take((size_t)C * per_step);

    auto cvt = [&](const float* s, bf16_t* d, int n) {
        int n4 = n >> 2;
        cvt_f32_bf16<<<dim3((n4 + 255) / 256), dim3(256), 0, stream>>>(s, d, n4);
    };
    cvt(p0, p0b, B_SZ * NP_SZ);
    cvt(e1w, e1wb, NH_SZ * NP_SZ);
    cvt(e2w, e2wb, NH_SZ * NP_SZ);
    cvt(whh, whhb, 4 * NH_SZ * NH_SZ);
    cvt(gw, gwb, NG_SZ * NH_SZ);
    cvt(decw, decwb, NP_SZ * NG_SZ);

    // encoders: hx0 (bf16), cx0 (f32). 64x64 tiles -> 128 blocks each, depth-4.
    gemm16<64, 64, 2, 2, 4, 1><<<dim3(NH_SZ / 64, B_SZ / 64), 256, 0, stream>>>(
        p0b, e1wb, e1b, hxA, B_SZ, NH_SZ, NP_SZ);
    gemm16<64, 64, 2, 2, 4, 0><<<dim3(NH_SZ / 64, B_SZ / 64), 256, 0, stream>>>(
        p0b, e2wb, e2b, cxf, B_SZ, NH_SZ, NP_SZ);

    // gates(0): hx(0)=hxA -> hx(1)=hxB. grid (16,8) = 128 blocks, 512 thr.
    gates_only<<<dim3(NH_SZ / 32, B_SZ / 128), 512, 0, stream>>>(
        hxA, whhb, v, wih, bih, bhh, cxf, hxB);

    bf16_t* cur = hxB;   // holds hx(t+1) at top of iteration t
    bf16_t* oth = hxA;
    for (int t = 0; t < T_STEPS; t++) {
        if (t < T_STEPS - 1) {
            // fused: g(t) (reads cur) || gates(t+1) (reads cur, writes oth = hx(t+2))
            fused_step<<<dim3(384), 512, 0, stream>>>(
                cur, gwb, gbuf + (size_t)(t % C) * B_SZ * NG_SZ,
                whhb, v + (size_t)(t + 1) * B_SZ * 2, wih, bih, bhh, cxf, oth);
        } else {
            g_only<<<dim3(256), 512, 0, stream>>>(
                cur, gwb, gbuf + (size_t)(t % C) * B_SZ * NG_SZ);
        }
        // chunked batched decoder: 256x256 tiles, 8 waves, depth-2 (96 KB LDS),
        // grid (2, C*B/256): staged = A x2 (420 MB) + B x(M/256) (400 MB) = 820 MB @ C=25
        if ((t + 1) % C == 0) {
            int t0 = t + 1 - C;
            gemm16<256, 256, 2, 4, 2, 0><<<dim3(NP_SZ / 256, (C * B_SZ) / 256), 512, 0, stream>>>(
                gbuf, decwb, decb, out + (size_t)t0 * B_SZ * NP_SZ, C * B_SZ, NP_SZ, NG_SZ);
        }
        bf16_t* tmp = cur; cur = oth; oth = tmp;
    }
}

// Round 10
// 1243.476 us; speedup vs baseline: 1.5076x; 1.2407x over previous
//
#include <hip/hip_runtime.h>
#include <hip/hip_bf16.h>

typedef __bf16 bf16_t;
typedef __bf16 bf16x4 __attribute__((ext_vector_type(4)));
typedef __bf16 bf16x8 __attribute__((ext_vector_type(8)));
typedef float f32x4 __attribute__((ext_vector_type(4)));

constexpr int T_STEPS = 50;
constexpr int B_SZ = 1024;
constexpr int NP_SZ = 512;
constexpr int NH_SZ = 512;
constexpr int NG_SZ = 4096;

// async 16B/lane global->LDS. LDS dest is wave-uniform base; HW deposits lane i at base + i*16.
__device__ __forceinline__ void async16(const bf16_t* g, bf16_t* l) {
    __builtin_amdgcn_global_load_lds((const __attribute__((address_space(1))) void*)g,
                                     (__attribute__((address_space(3))) void*)l, 16, 0, 0);
}

// Fused counted-vmcnt wait + workgroup barrier in ONE asm block with "memory" clobber.
// The builtin s_barrier is NOT a compiler memory fence (r5 race). The memory clobber
// pins all memory ops on their side; sched_barrier(0) pins the rest.
template <int N> __device__ __forceinline__ void wbar() {
    if constexpr (N == 0)       asm volatile("s_waitcnt vmcnt(0)\n\ts_barrier" ::: "memory");
    else if constexpr (N == 2)  asm volatile("s_waitcnt vmcnt(2)\n\ts_barrier" ::: "memory");
    else if constexpr (N == 3)  asm volatile("s_waitcnt vmcnt(3)\n\ts_barrier" ::: "memory");
    else if constexpr (N == 4)  asm volatile("s_waitcnt vmcnt(4)\n\ts_barrier" ::: "memory");
    else if constexpr (N == 6)  asm volatile("s_waitcnt vmcnt(6)\n\ts_barrier" ::: "memory");
    else if constexpr (N == 8)  asm volatile("s_waitcnt vmcnt(8)\n\ts_barrier" ::: "memory");
    else static_assert(N < 0, "add vmcnt literal");
    __builtin_amdgcn_sched_barrier(0);
}

// ---------------- fp32 -> bf16 convert ----------------
__global__ __launch_bounds__(256) void cvt_f32_bf16(const float* __restrict__ src,
                                                    bf16_t* __restrict__ dst, int n4) {
    int i = blockIdx.x * blockDim.x + threadIdx.x;
    if (i >= n4) return;
    float4 v = ((const float4*)src)[i];
    bf16x4 o;
    o[0] = (bf16_t)v.x; o[1] = (bf16_t)v.y; o[2] = (bf16_t)v.z; o[3] = (bf16_t)v.w;
    ((bf16x4*)dst)[i] = o;
}

// ---------------- counted-vmcnt depth-D GEMM template (encoders + decoder) ----------------
// WM x WN wave grid. LDS fragment order: chunk = 16 rows x 32 cols = 64 lanes x 16B;
// lane l holds rows (s*16+(l&15)), cols (l>>4)*8.. == its MFMA fragment. Interleaved
// chunk->wave mapping (s = q*NWAVES + wave) balances cold/hot staging across waves.
// DEPTH tiles in flight, NBUF=DEPTH+1; per-iter: wbar<(DEPTH-1)*PW> -> issue t+DEPTH
// -> ds_read+MFMA tile t. vmcnt never drains to 0 in the main loop.
// EP: 0 = +bias f32 out | 1 = +bias bf16 out | 2 = relu bf16 out
template <int BM, int BN, int WM, int WN, int DEPTH, int EP>
__global__ __launch_bounds__(WM * WN * 64) void gemm16(const bf16_t* __restrict__ A,
                                                       const bf16_t* __restrict__ Bm,
                                                       const float* __restrict__ bias,
                                                       void* __restrict__ Cout, int M, int N, int K) {
    constexpr int ASUB = BM / 16, BSUB = BN / 16, NSUB = ASUB + BSUB;
    constexpr int NWAVES = WM * WN;
    static_assert(NSUB % NWAVES == 0, "subtile split over waves");
    constexpr int PW = NSUB / NWAVES;
    constexpr int MT = BM / (16 * WM), NT = BN / (16 * WN);
    constexpr int BUF = NSUB * 512;
    constexpr int NBUF = DEPTH + 1;
    __shared__ bf16_t lds[NBUF * BUF];

    const int tid = threadIdx.x, lane = tid & 63, wave = tid >> 6;
    const int wm = wave / WN, wn = wave % WN;
    const int l15 = lane & 15, quad = lane >> 4;
    const int bm0 = blockIdx.y * BM, bn0 = blockIdx.x * BN;

    const bf16_t* gsrc[PW];
    bf16_t* ldst[PW];
#pragma unroll
    for (int q = 0; q < PW; q++) {
        int s = q * NWAVES + wave;
        if (s < ASUB)
            gsrc[q] = A + (size_t)(bm0 + s * 16 + l15) * K + quad * 8;
        else
            gsrc[q] = Bm + (size_t)(bn0 + (s - ASUB) * 16 + l15) * K + quad * 8;
        ldst[q] = &lds[s * 512];
    }

    f32x4 acc[MT][NT];
#pragma unroll
    for (int i = 0; i < MT; i++)
#pragma unroll
        for (int j = 0; j < NT; j++) acc[i][j] = f32x4{0.f, 0.f, 0.f, 0.f};

    auto compute = [&](int base) {
        bf16x8 af[MT], bfg[NT];
#pragma unroll
        for (int i = 0; i < MT; i++)
            af[i] = *(const bf16x8*)&lds[base + (wm * MT + i) * 512 + lane * 8];
#pragma unroll
        for (int j = 0; j < NT; j++)
            bfg[j] = *(const bf16x8*)&lds[base + (ASUB + wn * NT + j) * 512 + lane * 8];
#pragma unroll
        for (int i = 0; i < MT; i++)
#pragma unroll
            for (int j = 0; j < NT; j++)
                acc[i][j] = __builtin_amdgcn_mfma_f32_16x16x32_bf16(af[i], bfg[j], acc[i][j], 0, 0, 0);
    };

    const int nk = K / 32;  // launcher guarantees nk > DEPTH
#pragma unroll
    for (int d = 0; d < DEPTH; d++)
#pragma unroll
        for (int q = 0; q < PW; q++) async16(gsrc[q] + d * 32, ldst[q] + d * BUF);

    int cb = 0;
    for (int t = 0; t < nk - DEPTH; t++) {
        wbar<(DEPTH - 1) * PW>();
        int ib = cb + DEPTH; if (ib >= NBUF) ib -= NBUF;
#pragma unroll
        for (int q = 0; q < PW; q++) async16(gsrc[q] + (t + DEPTH) * 32, ldst[q] + ib * BUF);
        compute(cb * BUF);
        cb++; if (cb == NBUF) cb = 0;
    }
    wbar<0>();
    for (int t2 = 0; t2 < DEPTH; t2++) {
        compute(cb * BUF);
        cb++; if (cb == NBUF) cb = 0;
    }

#pragma unroll
    for (int j = 0; j < NT; j++) {
        const int col = bn0 + wn * (BN / WN) + j * 16 + l15;
        float bb = (EP == 2) ? 0.f : bias[col];
#pragma unroll
        for (int i = 0; i < MT; i++) {
#pragma unroll
            for (int r = 0; r < 4; r++) {
                const int row = bm0 + wm * (BM / WM) + i * 16 + quad * 4 + r;
                float x = acc[i][j][r];
                if constexpr (EP == 0) {
                    ((float*)Cout)[(size_t)row * N + col] = x + bb;
                } else if constexpr (EP == 1) {
                    ((bf16_t*)Cout)[(size_t)row * N + col] = (bf16_t)(x + bb);
                } else {
                    ((bf16_t*)Cout)[(size_t)row * N + col] = (bf16_t)fmaxf(x, 0.f);
                }
            }
        }
    }
}

// ================= per-step bodies (512 threads, 8 waves) =================
// g uses 3 x 24KB buffers = 72 KB; gates uses first 48 KB of the same array.
constexpr int STEP_LDS = 3 * 24 * 512;

// ---- g-GEMM body: g = relu(hx @ gw^T). 128x256 tile, WM=2 WN=4, DEPTH=2, K=512.
// 128 tiles: bx = n-tile (16), by = m-tile (8). Per-tile staging 384 KB; each wave
// stages 1 A + 2 B chunks per K-iter (interleaved s = q*8 + wave).
__device__ __forceinline__ void g_body(const bf16_t* __restrict__ A, const bf16_t* __restrict__ Bm,
                                       bf16_t* __restrict__ Cout, bf16_t* lds, int bx, int by) {
    constexpr int ASUB = 8, NSUB = 24, PW = 3, MT = 4, NT = 4, BUF = NSUB * 512, DEPTH = 2, NBUF = 3;
    const int tid = threadIdx.x, lane = tid & 63, wave = tid >> 6;
    const int wm = wave / 4, wn = wave % 4;
    const int l15 = lane & 15, quad = lane >> 4;
    const int bm0 = by * 128, bn0 = bx * 256;

    const bf16_t* gsrc[PW];
    bf16_t* ldst[PW];
#pragma unroll
    for (int q = 0; q < PW; q++) {
        int s = q * 8 + wave;
        if (s < ASUB)
            gsrc[q] = A + (size_t)(bm0 + s * 16 + l15) * NH_SZ + quad * 8;
        else
            gsrc[q] = Bm + (size_t)(bn0 + (s - ASUB) * 16 + l15) * NH_SZ + quad * 8;
        ldst[q] = &lds[s * 512];
    }

    f32x4 acc[MT][NT];
#pragma unroll
    for (int i = 0; i < MT; i++)
#pragma unroll
        for (int j = 0; j < NT; j++) acc[i][j] = f32x4{0.f, 0.f, 0.f, 0.f};

    auto compute = [&](int base) {
        bf16x8 af[MT], bfg[NT];
#pragma unroll
        for (int i = 0; i < MT; i++)
            af[i] = *(const bf16x8*)&lds[base + (wm * MT + i) * 512 + lane * 8];
#pragma unroll
        for (int j = 0; j < NT; j++)
            bfg[j] = *(const bf16x8*)&lds[base + (ASUB + wn * NT + j) * 512 + lane * 8];
#pragma unroll
        for (int i = 0; i < MT; i++)
#pragma unroll
            for (int j = 0; j < NT; j++)
                acc[i][j] = __builtin_amdgcn_mfma_f32_16x16x32_bf16(af[i], bfg[j], acc[i][j], 0, 0, 0);
    };

    constexpr int NK = NH_SZ / 32;  // 16
#pragma unroll
    for (int d = 0; d < DEPTH; d++)
#pragma unroll
        for (int q = 0; q < PW; q++) async16(gsrc[q] + d * 32, ldst[q] + d * BUF);

    int cb = 0;
    for (int t = 0; t < NK - DEPTH; t++) {
        wbar<(DEPTH - 1) * PW>();
        int ib = cb + DEPTH; if (ib >= NBUF) ib -= NBUF;
#pragma unroll
        for (int q = 0; q < PW; q++) async16(gsrc[q] + (t + DEPTH) * 32, ldst[q] + ib * BUF);
        compute(cb * BUF);
        cb++; if (cb == NBUF) cb = 0;
    }
    wbar<0>();
    for (int t2 = 0; t2 < DEPTH; t2++) {
        compute(cb * BUF);
        cb++; if (cb == NBUF) cb = 0;
    }

#pragma unroll
    for (int j = 0; j < NT; j++) {
        const int col = bn0 + wn * 64 + j * 16 + l15;
#pragma unroll
        for (int i = 0; i < MT; i++) {
#pragma unroll
            for (int r = 0; r < 4; r++) {
                const int row = bm0 + wm * 64 + i * 16 + quad * 4 + r;
                Cout[(size_t)row * NG_SZ + col] = (bf16_t)fmaxf(acc[i][j][r], 0.f);
            }
        }
    }
}

// ---- gates+cell body: 128(row b) x 32(col n) tile, 8 waves (wm=wave>>1 row-group of 32,
// wn=wave&1 col-half of 16), DEPTH=2, K=512. 128 tiles: bx (16) x by (8). Per-tile 256 KB;
// wave stages 1 A + 1 B chunk.
__device__ __forceinline__ void gates_body(const bf16_t* __restrict__ hx_in,
                                           const bf16_t* __restrict__ whh,
                                           const float* __restrict__ vt, const float* __restrict__ wih,
                                           const float* __restrict__ bih, const float* __restrict__ bhh,
                                           float* __restrict__ cx, bf16_t* __restrict__ hx_out,
                                           bf16_t* lds, int bx, int by) {
    constexpr int NSUB = 16, PW = 2, BUF = NSUB * 512, DEPTH = 2, NBUF = 3;
    const int tid = threadIdx.x, lane = tid & 63, wave = tid >> 6;
    const int wm = wave >> 1, wn = wave & 1;
    const int l15 = lane & 15, quad = lane >> 4;
    const int bm0 = by * 128, bn0 = bx * 32;

    // chunks: 0..7 = A (128 rows of hx), 8..15 = B (gate=(s-8)>>1, half=(s-8)&1)
    const bf16_t* gsrc[PW];
    bf16_t* ldst[PW];
#pragma unroll
    for (int q = 0; q < PW; q++) {
        int s = q * 8 + wave;
        if (s < 8) {
            gsrc[q] = hx_in + (size_t)(bm0 + s * 16 + l15) * NH_SZ + quad * 8;
        } else {
            int sb = s - 8, gi = sb >> 1, h = sb & 1;
            gsrc[q] = whh + (size_t)(gi * NH_SZ + bn0 + h * 16 + l15) * NH_SZ + quad * 8;
        }
        ldst[q] = &lds[s * 512];
    }

    f32x4 acc[4][2];
#pragma unroll
    for (int g = 0; g < 4; g++)
#pragma unroll
        for (int i = 0; i < 2; i++) acc[g][i] = f32x4{0.f, 0.f, 0.f, 0.f};

    auto compute = [&](int base) {
        bf16x8 af[2], bg[4];
#pragma unroll
        for (int i = 0; i < 2; i++)
            af[i] = *(const bf16x8*)&lds[base + (wm * 2 + i) * 512 + lane * 8];
#pragma unroll
        for (int g = 0; g < 4; g++)
            bg[g] = *(const bf16x8*)&lds[base + (8 + g * 2 + wn) * 512 + lane * 8];
#pragma unroll
        for (int g = 0; g < 4; g++)
#pragma unroll
            for (int i = 0; i < 2; i++)
                acc[g][i] = __builtin_amdgcn_mfma_f32_16x16x32_bf16(af[i], bg[g], acc[g][i], 0, 0, 0);
    };

    constexpr int NK = NH_SZ / 32;  // 16
#pragma unroll
    for (int d = 0; d < DEPTH; d++)
#pragma unroll
        for (int q = 0; q < PW; q++) async16(gsrc[q] + d * 32, ldst[q] + d * BUF);

    int cb = 0;
    for (int t = 0; t < NK - DEPTH; t++) {
        wbar<(DEPTH - 1) * PW>();
        int ib = cb + DEPTH; if (ib >= NBUF) ib -= NBUF;
#pragma unroll
        for (int q = 0; q < PW; q++) async16(gsrc[q] + (t + DEPTH) * 32, ldst[q] + ib * BUF);
        compute(cb * BUF);
        cb++; if (cb == NBUF) cb = 0;
    }
    wbar<0>();
    for (int t2 = 0; t2 < DEPTH; t2++) {
        compute(cb * BUF);
        cb++; if (cb == NBUF) cb = 0;
    }

    const int col = bn0 + wn * 16 + l15;
    float bi[4], w0[4], w1[4];
#pragma unroll
    for (int g = 0; g < 4; g++) {
        int gc = g * NH_SZ + col;
        bi[g] = bih[gc] + bhh[gc];
        w0[g] = wih[gc * 2];
        w1[g] = wih[gc * 2 + 1];
    }
#pragma unroll
    for (int i = 0; i < 2; i++) {
#pragma unroll
        for (int r = 0; r < 4; r++) {
            const int row = bm0 + wm * 32 + i * 16 + quad * 4 + r;
            float v0 = vt[row * 2], v1 = vt[row * 2 + 1];
            float xi = acc[0][i][r] + bi[0] + v0 * w0[0] + v1 * w1[0];
            float xf = acc[1][i][r] + bi[1] + v0 * w0[1] + v1 * w1[1];
            float xg = acc[2][i][r] + bi[2] + v0 * w0[2] + v1 * w1[2];
            float xo = acc[3][i][r] + bi[3] + v0 * w0[3] + v1 * w1[3];
            float ig = 1.f / (1.f + __expf(-xi));
            float fg = 1.f / (1.f + __expf(-xf));
            float gg = tanhf(xg);
            float og = 1.f / (1.f + __expf(-xo));
            int idx = (row << 9) + col;
            float c = fg * cx[idx] + ig * gg;
            cx[idx] = c;
            hx_out[idx] = (bf16_t)(og * tanhf(c));
        }
    }
}

// ---- standalone wrappers + fused kernel ----
__global__ __launch_bounds__(512) void gates_only(const bf16_t* hx_in, const bf16_t* whh,
                                                  const float* vt, const float* wih,
                                                  const float* bih, const float* bhh,
                                                  float* cx, bf16_t* hx_out) {
    __shared__ bf16_t lds[STEP_LDS];
    gates_body(hx_in, whh, vt, wih, bih, bhh, cx, hx_out, lds, blockIdx.x, blockIdx.y);
}

__global__ __launch_bounds__(512) void g_only(const bf16_t* hx, const bf16_t* gw, bf16_t* gout) {
    __shared__ bf16_t lds[STEP_LDS];
    g_body(hx, gw, gout, lds, blockIdx.x & 15, blockIdx.x >> 4);
}

// 256 blocks total (1/CU): 0..127 = g-GEMM(t) 128x256 tiles; 128..255 = gates(t+1).
// Both halves read hx(t+1); gates writes cx and hx(t+2) which g never touches.
__global__ __launch_bounds__(512) void fused_step(const bf16_t* hx, const bf16_t* gw, bf16_t* gout,
                                                  const bf16_t* whh, const float* vt_next,
                                                  const float* wih, const float* bih,
                                                  const float* bhh, float* cx, bf16_t* hx_next) {
    __shared__ bf16_t lds[STEP_LDS];
    const int id = blockIdx.x;
    if (id < 128) {
        g_body(hx, gw, gout, lds, id & 15, id >> 4);
    } else {
        const int j = id - 128;
        gates_body(hx, whh, vt_next, wih, bih, bhh, cx, hx_next, lds, j & 15, j >> 4);
    }
}

// ---------------- host launcher ----------------
extern "C" void kernel_launch(void* const* d_in, const int* in_sizes, int n_in,
                              void* d_out, int out_size, void* d_ws, size_t ws_size,
                              hipStream_t stream) {
    const float* v    = (const float*)d_in[0];
    const float* p0   = (const float*)d_in[1];
    const float* e1w  = (const float*)d_in[2];
    const float* e1b  = (const float*)d_in[3];
    const float* e2w  = (const float*)d_in[4];
    const float* e2b  = (const float*)d_in[5];
    const float* wih  = (const float*)d_in[6];
    const float* whh  = (const float*)d_in[7];
    const float* bih  = (const float*)d_in[8];
    const float* bhh  = (const float*)d_in[9];
    const float* gw   = (const float*)d_in[10];
    const float* decw = (const float*)d_in[11];
    const float* decb = (const float*)d_in[12];
    float* out = (float*)d_out;

    size_t off = 0;
    auto take = [&](size_t bytes) {
        size_t o = off;
        off += (bytes + 255) & ~(size_t)255;
        return (void*)((char*)d_ws + o);
    };
    bf16_t* p0b   = (bf16_t*)take((size_t)B_SZ * NP_SZ * 2);
    bf16_t* e1wb  = (bf16_t*)take((size_t)NH_SZ * NP_SZ * 2);
    bf16_t* e2wb  = (bf16_t*)take((size_t)NH_SZ * NP_SZ * 2);
    bf16_t* whhb  = (bf16_t*)take((size_t)4 * NH_SZ * NH_SZ * 2);
    bf16_t* gwb   = (bf16_t*)take((size_t)NG_SZ * NH_SZ * 2);
    bf16_t* decwb = (bf16_t*)take((size_t)NP_SZ * NG_SZ * 2);
    bf16_t* hxA   = (bf16_t*)take((size_t)B_SZ * NH_SZ * 2);
    bf16_t* hxB   = (bf16_t*)take((size_t)B_SZ * NH_SZ * 2);
    float*  cxf   = (float*)take((size_t)B_SZ * NH_SZ * 4);

    // decoder chunk size: largest divisor of T that fits remaining workspace
    const size_t per_step = (size_t)B_SZ * NG_SZ * 2;  // 8 MB bf16
    int C = 1;
    for (int c : {25, 10, 5, 2, 1}) {
        if (off + (size_t)c * per_step <= ws_size) { C = c; break; }
    }
    bf16_t* gbuf = (bf16_t*)take((size_t)C * per_step);

    auto cvt = [&](const float* s, bf16_t* d, int n) {
        int n4 = n >> 2;
        cvt_f32_bf16<<<dim3((n4 + 255) / 256), dim3(256), 0, stream>>>(s, d, n4);
    };
    cvt(p0, p0b, B_SZ * NP_SZ);
    cvt(e1w, e1wb, NH_SZ * NP_SZ);
    cvt(e2w, e2wb, NH_SZ * NP_SZ);
    cvt(whh, whhb, 4 * NH_SZ * NH_SZ);
    cvt(gw, gwb, NG_SZ * NH_SZ);
    cvt(decw, decwb, NP_SZ * NG_SZ);

    // encoders: hx0 (bf16), cx0 (f32). 64x64 tiles -> 128 blocks each, depth-4.
    gemm16<64, 64, 2, 2, 4, 1><<<dim3(NH_SZ / 64, B_SZ / 64), 256, 0, stream>>>(
        p0b, e1wb, e1b, hxA, B_SZ, NH_SZ, NP_SZ);
    gemm16<64, 64, 2, 2, 4, 0><<<dim3(NH_SZ / 64, B_SZ / 64), 256, 0, stream>>>(
        p0b, e2wb, e2b, cxf, B_SZ, NH_SZ, NP_SZ);

    // gates(0): hx(0)=hxA -> hx(1)=hxB. grid (16,8) = 128 blocks, 512 thr.
    gates_only<<<dim3(NH_SZ / 32, B_SZ / 128), 512, 0, stream>>>(
        hxA, whhb, v, wih, bih, bhh, cxf, hxB);

    bf16_t* cur = hxB;   // holds hx(t+1) at top of iteration t
    bf16_t* oth = hxA;
    for (int t = 0; t < T_STEPS; t++) {
        if (t < T_STEPS - 1) {
            // fused: g(t) 128 blocks || gates(t+1) 128 blocks -> 256 total, 1/CU
            fused_step<<<dim3(256), 512, 0, stream>>>(
                cur, gwb, gbuf + (size_t)(t % C) * B_SZ * NG_SZ,
                whhb, v + (size_t)(t + 1) * B_SZ * 2, wih, bih, bhh, cxf, oth);
        } else {
            g_only<<<dim3(128), 512, 0, stream>>>(
                cur, gwb, gbuf + (size_t)(t % C) * B_SZ * NG_SZ);
        }
        // chunked batched decoder: 256x256 tiles, 8 waves, depth-2 (96 KB LDS),
        // grid (2, C*B/256) = 200 blocks, ~4.1 MB staged per block (per-CU floor)
        if ((t + 1) % C == 0) {
            int t0 = t + 1 - C;
            gemm16<256, 256, 2, 4, 2, 0><<<dim3(NP_SZ / 256, (C * B_SZ) / 256), 512, 0, stream>>>(
                gbuf, decwb, decb, out + (size_t)t0 * B_SZ * NP_SZ, C * B_SZ, NP_SZ, NG_SZ);
        }
        bf16_t* tmp = cur; cur = oth; oth = tmp;
    }
}